// Round 12
// baseline (280.044 us; speedup 1.0000x reference)
//
#include <hip/hip_runtime.h>
#include <float.h>

#define CDIM 256
#define NPTS 2048
#define MPTS 4096
#define NB   4
#define KNN  16
#define COLS 64     // fused_mlp: NPB(4) * KNN
#define NCHUNK 8
#define CSIZE  512
#define NSTEPS 16
#define QPB   128   // score_knn queries per block

typedef _Float16 half8 __attribute__((ext_vector_type(8)));
typedef _Float16 half4 __attribute__((ext_vector_type(4)));
typedef float    f32x4 __attribute__((ext_vector_type(4)));

// swizzled byte offsets: row stride 512B / 128B
__device__ __forceinline__ int swzS(int row, int byte) {
    return row * 512 + (byte ^ ((row & 7) << 4));
}
__device__ __forceinline__ int swz128(int row, int byte) {
    return row * 128 + (byte ^ ((row & 7) << 4));
}

// 16-lane (DPP row) sum via rotations; every lane ends with the total.
__device__ __forceinline__ float sum16(float v) {
    v += __uint_as_float(__builtin_amdgcn_update_dpp(0, __float_as_uint(v), 0x128, 0xF, 0xF, true));
    v += __uint_as_float(__builtin_amdgcn_update_dpp(0, __float_as_uint(v), 0x124, 0xF, 0xF, true));
    v += __uint_as_float(__builtin_amdgcn_update_dpp(0, __float_as_uint(v), 0x122, 0xF, 0xF, true));
    v += __uint_as_float(__builtin_amdgcn_update_dpp(0, __float_as_uint(v), 0x121, 0xF, 0xF, true));
    return v;
}

// compare-exchange: kk ascending
#define CEA(x, y)                                                               \
    { unsigned lo_ = kk[x] < kk[y] ? kk[x] : kk[y];                             \
      unsigned hi_ = kk[x] < kk[y] ? kk[y] : kk[x];                             \
      kk[x] = lo_; kk[y] = hi_; }
// compare-exchange: td descending (max to lower index)
#define CED(x, y)                                                               \
    { unsigned hi_ = td[x] > td[y] ? td[x] : td[y];                             \
      unsigned lo_ = td[x] > td[y] ? td[y] : td[x];                             \
      td[x] = hi_; td[y] = lo_; }
// bitonic-16 -> sorted descending (spans 8,4,2,1)
#define RESORT16                                                                \
    CED(0,8) CED(1,9) CED(2,10) CED(3,11) CED(4,12) CED(5,13) CED(6,14) CED(7,15) \
    CED(0,4) CED(1,5) CED(2,6) CED(3,7) CED(8,12) CED(9,13) CED(10,14) CED(11,15) \
    CED(0,2) CED(1,3) CED(4,6) CED(5,7) CED(8,10) CED(9,11) CED(12,14) CED(13,15) \
    CED(0,1) CED(2,3) CED(4,5) CED(6,7) CED(8,9) CED(10,11) CED(12,13) CED(14,15)

// ------- (B,C,M) fp32 -> featH/featL (B,M,C) f16 hi/lo + r2, tiled & coalesced
__global__ __launch_bounds__(256) void tposeHL2(const float* __restrict__ feat,
                                                const float* __restrict__ featdb,
                                                _Float16* __restrict__ featH,
                                                _Float16* __restrict__ featL,
                                                float* __restrict__ r2) {
    __shared__ float red[8][33];
    const int b = blockIdx.y;
    const int mt = blockIdx.x;
    const int m = threadIdx.x & 31;
    const int cp = threadIdx.x >> 5;
    const int mg = mt * 32 + m;
    const float* src = (mg < NPTS) ? (feat + (size_t)b * CDIM * NPTS + mg)
                                   : (featdb + (size_t)b * CDIM * NPTS + (mg - NPTS));
    const int c0 = cp * 32;
    float acc = 0.f;
    half8 hh[4], ll[4];
#pragma unroll
    for (int i = 0; i < 32; i++) {
        float v = src[(size_t)(c0 + i) * NPTS];
        acc += v * v;
        _Float16 h = (_Float16)v;
        hh[i >> 3][i & 7] = h;
        ll[i >> 3][i & 7] = (_Float16)(v - (float)h);
    }
    _Float16* dh = featH + ((size_t)b * MPTS + mg) * CDIM + c0;
    _Float16* dl = featL + ((size_t)b * MPTS + mg) * CDIM + c0;
#pragma unroll
    for (int i = 0; i < 4; i++) {
        *(half8*)(dh + i * 8) = hh[i];
        *(half8*)(dl + i * 8) = ll[i];
    }
    red[cp][m] = acc;
    __syncthreads();
    if (threadIdx.x < 32) {
        float s = 0.f;
#pragma unroll
        for (int j = 0; j < 8; j++) s += red[j][threadIdx.x];
        r2[b * MPTS + mt * 32 + threadIdx.x] = s;
    }
}

// ------- weights fp32 -> f16
__global__ __launch_bounds__(256) void wcvt(const float* __restrict__ aw1,
                                            const float* __restrict__ aw2,
                                            const float* __restrict__ pw2,
                                            _Float16* __restrict__ aw1h,
                                            _Float16* __restrict__ aw2h,
                                            _Float16* __restrict__ pw2h) {
    int i = blockIdx.x * 256 + threadIdx.x;
    if (i < 65536) { aw1h[i] = (_Float16)aw1[i]; aw2h[i] = (_Float16)aw2[i]; }
    if (i < 16384) { pw2h[i] = (_Float16)pw2[i]; }
}

// ------- distance GEMM (f16 hi/lo) + bitonic top-16.
// 512 threads = 8 waves = 128 queries/block sharing each staged ref tile:
// staging bytes per query halved, 16 waves/CU resident (was 8).
__global__ __launch_bounds__(512, 4) void score_knn(const _Float16* __restrict__ featH,
                                                    const _Float16* __restrict__ featL,
                                                    const float* __restrict__ r2g,
                                                    unsigned* __restrict__ partial) {
    __shared__ __align__(16) char sbuf[65536];   // 2 x (smH 16K | smL 16K)
    __shared__ float sr2[CSIZE];

    const int tid = threadIdx.x;
    const int lane = tid & 63, wave = tid >> 6;   // 8 waves
    const int l15 = lane & 15, l4 = lane >> 4;
    const int chunk = blockIdx.x, qt = blockIdx.y, b = blockIdx.z;
    const int nq = qt * QPB + wave * 16 + l15;
    const int m0 = chunk * CSIZE;

    sr2[tid] = r2g[b * MPTS + m0 + tid];   // 512 == CSIZE

    half8 qh[8], ql[8];
    {
        const _Float16* qb = featH + ((size_t)b * MPTS + nq) * CDIM + l4 * 8;
        const _Float16* qL = featL + ((size_t)b * MPTS + nq) * CDIM + l4 * 8;
#pragma unroll
        for (int ks = 0; ks < 8; ks++) {
            qh[ks] = *(const half8*)(qb + ks * 32);
            ql[ks] = *(const half8*)(qL + ks * 32);
        }
    }

    // step-invariant LDS read addresses (octet o = ks*4+l4; XOR key = (o>>2)&7 = ks&7)
    int adr[8];
#pragma unroll
    for (int ks = 0; ks < 8; ks++)
        adr[ks] = (ks * 4 + l4) * 512 + ((l15 * 16) ^ ((ks & 7) << 4));

    // staging: 2 16B-units per thread: row = tid>>4 (0..31), o = 2*(tid&15)+j
    const int srow = tid >> 4;
    const int o0 = 2 * (tid & 15);
    int wadr[2];
#pragma unroll
    for (int j = 0; j < 2; j++) {
        int o = o0 + j;
        wadr[j] = o * 512 + ((srow * 16) ^ (((o >> 2) & 7) << 4));
    }
    const char* gH = (const char*)(featH + ((size_t)b * MPTS + m0 + srow) * CDIM) + o0 * 16;
    const char* gL = (const char*)(featL + ((size_t)b * MPTS + m0 + srow) * CDIM) + o0 * 16;

    unsigned td[16];
#pragma unroll
    for (int i = 0; i < 16; i++) td[i] = 0xFFFFFFFFu;

    half8 pH[2], pL[2];
#pragma unroll
    for (int j = 0; j < 2; j++) {
        pH[j] = *(const half8*)(gH + j * 16);
        pL[j] = *(const half8*)(gL + j * 16);
    }
    gH += 32 * CDIM * 2;
    gL += 32 * CDIM * 2;

    for (int s = 0; s < NSTEPS; ++s) {
        char* buf = sbuf + (s & 1) * 32768;
#pragma unroll
        for (int j = 0; j < 2; j++) {
            *(half8*)(buf + wadr[j])         = pH[j];
            *(half8*)(buf + 16384 + wadr[j]) = pL[j];
        }
        __syncthreads();

        if (s < NSTEPS - 1) {
#pragma unroll
            for (int j = 0; j < 2; j++) {
                pH[j] = *(const half8*)(gH + j * 16);
                pL[j] = *(const half8*)(gL + j * 16);
            }
            gH += 32 * CDIM * 2;
            gL += 32 * CDIM * 2;
        }

        unsigned kk[8];
#pragma unroll
        for (int sub = 0; sub < 2; ++sub) {
            f32x4 a0 = {0.f, 0.f, 0.f, 0.f};
            f32x4 a1 = {0.f, 0.f, 0.f, 0.f};
            f32x4 a2 = {0.f, 0.f, 0.f, 0.f};
#pragma unroll
            for (int ks = 0; ks < 8; ks++) {
                half8 ah = *(const half8*)(buf + adr[ks] + sub * 256);
                half8 al = *(const half8*)(buf + 16384 + adr[ks] + sub * 256);
                a0 = __builtin_amdgcn_mfma_f32_16x16x32_f16(ah, qh[ks], a0, 0, 0, 0);
                a1 = __builtin_amdgcn_mfma_f32_16x16x32_f16(ah, ql[ks], a1, 0, 0, 0);
                a2 = __builtin_amdgcn_mfma_f32_16x16x32_f16(al, qh[ks], a2, 0, 0, 0);
            }
            float4 s4 = *(const float4*)(sr2 + s * 32 + sub * 16 + 4 * l4);
            const float sv[4] = {s4.x, s4.y, s4.z, s4.w};
            const int mloc0 = s * 32 + sub * 16 + 4 * l4;
#pragma unroll
            for (int r = 0; r < 4; r++) {
                float d = fmaxf(sv[r] - 2.f * (a0[r] + a1[r] + a2[r]), 0.f);
                unsigned dq = (unsigned)(d * 4096.f);
                dq = dq > 0x7FFFF0u ? 0x7FFFF0u : dq;
                kk[sub * 4 + r] = (dq << 9) | (unsigned)(mloc0 + r);
            }
        }
        CEA(0,1) CEA(2,3) CEA(4,5) CEA(6,7)
        CEA(0,2) CEA(1,3) CEA(4,6) CEA(5,7)
        CEA(1,2) CEA(5,6) CEA(0,4) CEA(3,7)
        CEA(1,5) CEA(2,6)
        CEA(1,4) CEA(3,6)
        CEA(2,4) CEA(3,5)
        CEA(3,4)
#pragma unroll
        for (int i = 0; i < 8; i++) td[i] = td[i] < kk[i] ? td[i] : kk[i];
        RESORT16
    }

    // merge the 4 per-lane sorted lists via xor-shuffle bitonic merges
#pragma unroll
    for (int rr = 0; rr < 2; rr++) {
        const int dx = 16 << rr;
        unsigned ot[16];
#pragma unroll
        for (int e = 0; e < 16; e++) ot[e] = __shfl_xor(td[e], dx);
#pragma unroll
        for (int e = 0; e < 16; e++) {
            unsigned o = ot[15 - e];
            td[e] = td[e] < o ? td[e] : o;
        }
        RESORT16
    }
    if (l4 == 0) {
        const size_t qrow = (size_t)b * NPTS + qt * QPB + wave * 16 + l15;
#pragma unroll
        for (int e = 0; e < 16; e++)
            partial[(size_t)(chunk * 16 + e) * (NB * NPTS) + qrow] = td[e];
    }
}

// ------- final merge: NCHUNK x 16 keys -> top-16 indices per row
__global__ __launch_bounds__(256) void merge16(const unsigned* __restrict__ partial,
                                               int* __restrict__ idxout) {
    const int row = blockIdx.x * 256 + threadIdx.x;
    unsigned long long td[16];
#pragma unroll
    for (int i = 0; i < 16; i++) td[i] = 0x8000000000ull + (unsigned long long)i;
    unsigned long long curmax = 0x800000000Full;
    for (int e = 0; e < NCHUNK * 16; e++) {
        unsigned k = partial[(size_t)e * (NB * NPTS) + row];
        unsigned long long k64 =
            (((unsigned long long)(k >> 9)) << 12) |
            (unsigned long long)((unsigned)((e >> 4) << 9) | (k & 0x1FFu));
        if (k64 < curmax) {
#pragma unroll
            for (int i_ = 0; i_ < 16; i_++) td[i_] = (td[i_] == curmax) ? k64 : td[i_];
            unsigned long long nm_ = td[0];
#pragma unroll
            for (int i_ = 1; i_ < 16; i_++) nm_ = td[i_] > nm_ ? td[i_] : nm_;
            curmax = nm_;
        }
    }
#pragma unroll
    for (int e = 0; e < 16; e++) idxout[row * 16 + e] = (int)(td[e] & 0xFFFull);
}

// ------- fused MLP chain on f16 MFMA. block = 4 points = 64 cols, 8 waves.
// pe lives ONLY in regs (pe4); x computed at output layout from 8B fn/fm
// gathers (single-pass xbuf write, no LDS round-trip). fm4 kept in regs --
// the epilogue's group_feat gather is the identical address, so it's free.
// hbuf aliases xbuf (dead before xbuf's first write). LDS ~36 KB.
__global__ __launch_bounds__(512, 4) void fused_mlp7(
    const float* __restrict__ pcd, const float* __restrict__ pcddb,
    const _Float16* __restrict__ featH, const int* __restrict__ knn,
    const float* __restrict__ pw1, const float* __restrict__ pb1,
    const float* __restrict__ pg, const float* __restrict__ pbe,
    const float* __restrict__ pm, const float* __restrict__ pv,
    const _Float16* __restrict__ pw2h, const float* __restrict__ pb2,
    const _Float16* __restrict__ aw1h, const float* __restrict__ ab1,
    const float* __restrict__ ag, const float* __restrict__ abe,
    const float* __restrict__ am, const float* __restrict__ av,
    const _Float16* __restrict__ aw2h,
    float* __restrict__ out) {
    __shared__ __align__(16) char smem[COLS * 256 * 2];   // hbuf (8KB) -> x -> a1
    _Float16* xbuf = (_Float16*)smem;
    _Float16* hbuf = (_Float16*)smem;
    __shared__ __align__(16) float pr[3][COLS];
    __shared__ int sidx[COLS];
    __shared__ __align__(16) float ainv[256], ash2[256], pinv[64], psh[64];

    const int tid = threadIdx.x;
    const int lane = tid & 63, wave = tid >> 6;
    const int l15 = lane & 15, l4 = lane >> 4;
    const int blk = blockIdx.x;
    const int b = blk >> 9;
    const int n0 = (blk & 511) * 4;
    const int R0 = wave * 32;

    // ---- phase 0: consts + sidx; preload pw2 fragments
    if (tid < COLS) {
        sidx[tid] = knn[(size_t)(b * NPTS + n0 + (tid >> 4)) * KNN + (tid & 15)];
    } else if (tid < COLS + 256) {
        int c = tid - COLS;
        float inv = ag[c] / sqrtf(av[c] + 1e-5f);
        ainv[c] = inv;
        ash2[c] = abe[c] - am[c] * inv + ab1[c] * inv;
    } else if (tid < COLS + 256 + 64) {
        int o = tid - COLS - 256;
        float inv = pg[o] / sqrtf(pv[o] + 1e-5f);
        pinv[o] = inv;
        psh[o] = pbe[o] - pm[o] * inv;
    }
    half8 wp[2][2];
#pragma unroll
    for (int rt = 0; rt < 2; rt++)
#pragma unroll
        for (int ks = 0; ks < 2; ks++)
            wp[rt][ks] = *(const half8*)(pw2h + (size_t)(R0 + rt * 16 + l15) * 64 +
                                         ks * 32 + l4 * 8);
    __syncthreads();

    // ---- phase 1: pr gather
    if (tid < 3 * COLS) {
        int c = tid >> 6, col = tid & 63;
        int m = sidx[col];
        const float* pc = pcd + ((size_t)b * 3 + c) * NPTS;
        const float* px = pcddb + ((size_t)b * 3 + c) * NPTS;
        float gp = (m < NPTS) ? pc[m] : px[m - NPTS];
        pr[c][col] = pc[n0 + (col >> 4)] - gp;
    }
    __syncthreads();

    // ---- phase 2: h = relu(bn(pw1 @ pos_rel)) -> hbuf [col][64]
    {
        int col = tid >> 3, o0 = (tid & 7) * 8;
        float x0 = pr[0][col], x1 = pr[1][col], x2 = pr[2][col];
        half8 hv;
#pragma unroll
        for (int i = 0; i < 8; i++) {
            int o = o0 + i;
            float v = pw1[o * 3] * x0 + pw1[o * 3 + 1] * x1 + pw1[o * 3 + 2] * x2 + pb1[o];
            v = fmaxf(v * pinv[o] + psh[o], 0.f);
            hv[i] = (_Float16)v;
        }
        *(half8*)((char*)hbuf + swz128(col, o0 * 2)) = hv;
    }
    __syncthreads();

    // ---- phase 3: pe GEMM -> registers pe4 only (no LDS write)
    f32x4 acc[2][4];
#pragma unroll
    for (int rt = 0; rt < 2; rt++)
#pragma unroll
        for (int ct = 0; ct < 4; ct++) acc[rt][ct] = (f32x4){0.f, 0.f, 0.f, 0.f};
#pragma unroll
    for (int ks = 0; ks < 2; ks++) {
        int k0 = ks * 32 + l4 * 8;
#pragma unroll
        for (int ct = 0; ct < 4; ct++) {
            half8 bb = *(const half8*)((char*)hbuf + swz128(ct * 16 + l15, k0 * 2));
            acc[0][ct] = __builtin_amdgcn_mfma_f32_16x16x32_f16(wp[0][ks], bb, acc[0][ct], 0, 0, 0);
            acc[1][ct] = __builtin_amdgcn_mfma_f32_16x16x32_f16(wp[1][ks], bb, acc[1][ct], 0, 0, 0);
        }
    }
    half4 pe4[2][4];
#pragma unroll
    for (int rt = 0; rt < 2; rt++) {
        int cb = R0 + rt * 16 + 4 * l4;
        float4 pb = *(const float4*)(pb2 + cb);
        float pbv[4] = {pb.x, pb.y, pb.z, pb.w};
#pragma unroll
        for (int ct = 0; ct < 4; ct++) {
            half4 p4;
#pragma unroll
            for (int r = 0; r < 4; r++) p4[r] = (_Float16)(acc[rt][ct][r] + pbv[r]);
            pe4[rt][ct] = p4;
        }
    }
    __syncthreads();   // hbuf dead; xbuf region free

    // ---- phase 4: x = fn - fm + pe4 at output layout -> xbuf (single pass);
    //               fm4 retained for the epilogue. preload aw1 rt0.
    half4 fm4[2][4];
#pragma unroll
    for (int rt = 0; rt < 2; rt++) {
        int cb = R0 + rt * 16 + 4 * l4;
#pragma unroll
        for (int ct = 0; ct < 4; ct++) {
            int col = ct * 16 + l15;
            half4 fn4 = *(const half4*)(featH + ((size_t)b * MPTS + n0 + ct) * CDIM + cb);
            half4 fm = *(const half4*)(featH + ((size_t)b * MPTS + sidx[col]) * CDIM + cb);
            fm4[rt][ct] = fm;
            half4 xv = fn4 - fm + pe4[rt][ct];
            *(half4*)((char*)xbuf + swzS(col, cb * 2)) = xv;
        }
    }
    half8 wa[8];
#pragma unroll
    for (int ks = 0; ks < 8; ks++)
        wa[ks] = *(const half8*)(aw1h + (size_t)(R0 + l15) * 256 + ks * 32 + l4 * 8);
    __syncthreads();

    // ---- phase 5: GEMM1, one rt at a time (32 weight regs peak)
#pragma unroll
    for (int rt = 0; rt < 2; rt++)
#pragma unroll
        for (int ct = 0; ct < 4; ct++) acc[rt][ct] = (f32x4){0.f, 0.f, 0.f, 0.f};
#pragma unroll
    for (int ks = 0; ks < 8; ks++) {
        int k0 = ks * 32 + l4 * 8;
#pragma unroll
        for (int ct = 0; ct < 4; ct++) {
            half8 bb = *(const half8*)((char*)xbuf + swzS(ct * 16 + l15, k0 * 2));
            acc[0][ct] = __builtin_amdgcn_mfma_f32_16x16x32_f16(wa[ks], bb, acc[0][ct], 0, 0, 0);
        }
    }
#pragma unroll
    for (int ks = 0; ks < 8; ks++)
        wa[ks] = *(const half8*)(aw1h + (size_t)(R0 + 16 + l15) * 256 + ks * 32 + l4 * 8);
#pragma unroll
    for (int ks = 0; ks < 8; ks++) {
        int k0 = ks * 32 + l4 * 8;
#pragma unroll
        for (int ct = 0; ct < 4; ct++) {
            half8 bb = *(const half8*)((char*)xbuf + swzS(ct * 16 + l15, k0 * 2));
            acc[1][ct] = __builtin_amdgcn_mfma_f32_16x16x32_f16(wa[ks], bb, acc[1][ct], 0, 0, 0);
        }
    }
    __syncthreads();

    // ---- phase 6: a1 = relu(bn(.)) -> xbuf; preload aw2 rt0
#pragma unroll
    for (int rt = 0; rt < 2; rt++) {
        int cb = R0 + rt * 16 + 4 * l4;
        float4 iv = *(const float4*)(&ainv[cb]);
        float4 sh = *(const float4*)(&ash2[cb]);
        float ivv[4] = {iv.x, iv.y, iv.z, iv.w};
        float shv[4] = {sh.x, sh.y, sh.z, sh.w};
#pragma unroll
        for (int ct = 0; ct < 4; ct++) {
            int col = ct * 16 + l15;
            half4 h4;
#pragma unroll
            for (int r = 0; r < 4; r++)
                h4[r] = (_Float16)fmaxf(acc[rt][ct][r] * ivv[r] + shv[r], 0.f);
            *(half4*)((char*)xbuf + swzS(col, cb * 2)) = h4;
        }
    }
#pragma unroll
    for (int ks = 0; ks < 8; ks++)
        wa[ks] = *(const half8*)(aw2h + (size_t)(R0 + l15) * 256 + ks * 32 + l4 * 8);
    __syncthreads();

    // ---- phase 7: GEMM2, one rt at a time
#pragma unroll
    for (int rt = 0; rt < 2; rt++)
#pragma unroll
        for (int ct = 0; ct < 4; ct++) acc[rt][ct] = (f32x4){0.f, 0.f, 0.f, 0.f};
#pragma unroll
    for (int ks = 0; ks < 8; ks++) {
        int k0 = ks * 32 + l4 * 8;
#pragma unroll
        for (int ct = 0; ct < 4; ct++) {
            half8 bb = *(const half8*)((char*)xbuf + swzS(ct * 16 + l15, k0 * 2));
            acc[0][ct] = __builtin_amdgcn_mfma_f32_16x16x32_f16(wa[ks], bb, acc[0][ct], 0, 0, 0);
        }
    }
#pragma unroll
    for (int ks = 0; ks < 8; ks++)
        wa[ks] = *(const half8*)(aw2h + (size_t)(R0 + 16 + l15) * 256 + ks * 32 + l4 * 8);
#pragma unroll
    for (int ks = 0; ks < 8; ks++) {
        int k0 = ks * 32 + l4 * 8;
#pragma unroll
        for (int ct = 0; ct < 4; ct++) {
            half8 bb = *(const half8*)((char*)xbuf + swzS(ct * 16 + l15, k0 * 2));
            acc[1][ct] = __builtin_amdgcn_mfma_f32_16x16x32_f16(wa[ks], bb, acc[1][ct], 0, 0, 0);
        }
    }

    // ---- epilogue: DPP softmax; sv = fm4 + pe4 (both already in regs)
#pragma unroll
    for (int rt = 0; rt < 2; rt++) {
        int cb = R0 + rt * 16 + 4 * l4;
#pragma unroll
        for (int ct = 0; ct < 4; ct++) {
            float oo[4], ss[4];
#pragma unroll
            for (int r = 0; r < 4; r++) {
                float v = acc[rt][ct][r];
                v = fminf(fmaxf(v, -60.f), 60.f);
                float e = __expf(v);
                float sv = (float)fm4[rt][ct][r] + (float)pe4[rt][ct][r];
                ss[r] = sum16(e);
                oo[r] = sum16(e * sv);
            }
            if (l15 < 4) {
                float o = l15 == 0 ? oo[0] : l15 == 1 ? oo[1] : l15 == 2 ? oo[2] : oo[3];
                float s = l15 == 0 ? ss[0] : l15 == 1 ? ss[1] : l15 == 2 ? ss[2] : ss[3];
                out[((size_t)b * CDIM + cb + l15) * NPTS + n0 + ct] =
                    o * __builtin_amdgcn_rcpf(s);
            }
        }
    }
}

// ------------------------------------------------------------------- launch
extern "C" void kernel_launch(void* const* d_in, const int* in_sizes, int n_in,
                              void* d_out, int out_size, void* d_ws, size_t ws_size,
                              hipStream_t stream) {
    const float* pcd    = (const float*)d_in[0];
    const float* feat   = (const float*)d_in[1];
    const float* pcddb  = (const float*)d_in[2];
    const float* featdb = (const float*)d_in[3];
    const float* pw1 = (const float*)d_in[4];
    const float* pb1 = (const float*)d_in[5];
    const float* pg  = (const float*)d_in[6];
    const float* pbe = (const float*)d_in[7];
    const float* pm  = (const float*)d_in[8];
    const float* pv  = (const float*)d_in[9];
    const float* pw2 = (const float*)d_in[10];
    const float* pb2 = (const float*)d_in[11];
    const float* aw1 = (const float*)d_in[12];
    const float* ab1 = (const float*)d_in[13];
    const float* ag  = (const float*)d_in[14];
    const float* abe = (const float*)d_in[15];
    const float* am  = (const float*)d_in[16];
    const float* av  = (const float*)d_in[17];
    const float* aw2 = (const float*)d_in[18];
    // d_in[19] = ab2: constant over k -> cancels in softmax, unused
    float* out = (float*)d_out;

    char* ws = (char*)d_ws;
    _Float16* featH   = (_Float16*)(ws);               // 8 MB
    _Float16* featL   = (_Float16*)(ws + 8388608);     // 8 MB
    float*    ws_r2   = (float*)(ws + 16777216);       // 64 KB
    unsigned* partial = (unsigned*)(ws + 16842752);    // 4 MB
    int*      ws_idx  = (int*)(ws + 21037056);         // 512 KB
    _Float16* aw1h    = (_Float16*)(ws + 21561344);    // 128 KB
    _Float16* aw2h    = (_Float16*)(ws + 21692416);    // 128 KB
    _Float16* pw2h    = (_Float16*)(ws + 21823488);    // 32 KB

    wcvt<<<256, 256, 0, stream>>>(aw1, aw2, pw2, aw1h, aw2h, pw2h);
    tposeHL2<<<dim3(MPTS / 32, NB), 256, 0, stream>>>(feat, featdb, featH, featL, ws_r2);
    score_knn<<<dim3(NCHUNK, NPTS / QPB, NB), 512, 0, stream>>>(featH, featL, ws_r2, partial);
    merge16<<<NB * NPTS / 256, 256, 0, stream>>>(partial, ws_idx);
    fused_mlp7<<<NB * (NPTS / 4), 512, 0, stream>>>(
        pcd, pcddb, featH, ws_idx,
        pw1, pb1, pg, pbe, pm, pv, pw2h, pb2,
        aw1h, ab1, ag, abe, am, av, aw2h, out);
}

// Round 14
// 272.377 us; speedup vs baseline: 1.0281x; 1.0281x over previous
//
#include <hip/hip_runtime.h>
#include <float.h>

#define CDIM 256
#define NPTS 2048
#define MPTS 4096
#define NB   4
#define KNN  16
#define COLS 64     // fused_mlp: NPB(4) * KNN
#define NCHUNK 8
#define CSIZE  512
#define NSTEPS 16
#define QPB   128   // score_knn queries per block

typedef _Float16 half8 __attribute__((ext_vector_type(8)));
typedef _Float16 half4 __attribute__((ext_vector_type(4)));
typedef float    f32x4 __attribute__((ext_vector_type(4)));

// swizzled byte offsets: row stride 512B / 128B
__device__ __forceinline__ int swzS(int row, int byte) {
    return row * 512 + (byte ^ ((row & 7) << 4));
}
__device__ __forceinline__ int swz128(int row, int byte) {
    return row * 128 + (byte ^ ((row & 7) << 4));
}

// 16-lane (DPP row) sum via rotations; every lane ends with the total.
__device__ __forceinline__ float sum16(float v) {
    v += __uint_as_float(__builtin_amdgcn_update_dpp(0, __float_as_uint(v), 0x128, 0xF, 0xF, true));
    v += __uint_as_float(__builtin_amdgcn_update_dpp(0, __float_as_uint(v), 0x124, 0xF, 0xF, true));
    v += __uint_as_float(__builtin_amdgcn_update_dpp(0, __float_as_uint(v), 0x122, 0xF, 0xF, true));
    v += __uint_as_float(__builtin_amdgcn_update_dpp(0, __float_as_uint(v), 0x121, 0xF, 0xF, true));
    return v;
}

// compare-exchange: kk ascending
#define CEA(x, y)                                                               \
    { unsigned lo_ = kk[x] < kk[y] ? kk[x] : kk[y];                             \
      unsigned hi_ = kk[x] < kk[y] ? kk[y] : kk[x];                             \
      kk[x] = lo_; kk[y] = hi_; }
// compare-exchange: td descending (max to lower index)
#define CED(x, y)                                                               \
    { unsigned hi_ = td[x] > td[y] ? td[x] : td[y];                             \
      unsigned lo_ = td[x] > td[y] ? td[y] : td[x];                             \
      td[x] = hi_; td[y] = lo_; }
// bitonic-16 -> sorted descending (spans 8,4,2,1)
#define RESORT16                                                                \
    CED(0,8) CED(1,9) CED(2,10) CED(3,11) CED(4,12) CED(5,13) CED(6,14) CED(7,15) \
    CED(0,4) CED(1,5) CED(2,6) CED(3,7) CED(8,12) CED(9,13) CED(10,14) CED(11,15) \
    CED(0,2) CED(1,3) CED(4,6) CED(5,7) CED(8,10) CED(9,11) CED(12,14) CED(13,15) \
    CED(0,1) CED(2,3) CED(4,5) CED(6,7) CED(8,9) CED(10,11) CED(12,13) CED(14,15)

// ------- (B,C,M) fp32 -> featH/featL (B,M,C) f16 hi/lo + r2, tiled & coalesced
__global__ __launch_bounds__(256) void tposeHL2(const float* __restrict__ feat,
                                                const float* __restrict__ featdb,
                                                _Float16* __restrict__ featH,
                                                _Float16* __restrict__ featL,
                                                float* __restrict__ r2) {
    __shared__ float red[8][33];
    const int b = blockIdx.y;
    const int mt = blockIdx.x;
    const int m = threadIdx.x & 31;
    const int cp = threadIdx.x >> 5;
    const int mg = mt * 32 + m;
    const float* src = (mg < NPTS) ? (feat + (size_t)b * CDIM * NPTS + mg)
                                   : (featdb + (size_t)b * CDIM * NPTS + (mg - NPTS));
    const int c0 = cp * 32;
    float acc = 0.f;
    half8 hh[4], ll[4];
#pragma unroll
    for (int i = 0; i < 32; i++) {
        float v = src[(size_t)(c0 + i) * NPTS];
        acc += v * v;
        _Float16 h = (_Float16)v;
        hh[i >> 3][i & 7] = h;
        ll[i >> 3][i & 7] = (_Float16)(v - (float)h);
    }
    _Float16* dh = featH + ((size_t)b * MPTS + mg) * CDIM + c0;
    _Float16* dl = featL + ((size_t)b * MPTS + mg) * CDIM + c0;
#pragma unroll
    for (int i = 0; i < 4; i++) {
        *(half8*)(dh + i * 8) = hh[i];
        *(half8*)(dl + i * 8) = ll[i];
    }
    red[cp][m] = acc;
    __syncthreads();
    if (threadIdx.x < 32) {
        float s = 0.f;
#pragma unroll
        for (int j = 0; j < 8; j++) s += red[j][threadIdx.x];
        r2[b * MPTS + mt * 32 + threadIdx.x] = s;
    }
}

// ------- weights fp32 -> f16
__global__ __launch_bounds__(256) void wcvt(const float* __restrict__ aw1,
                                            const float* __restrict__ aw2,
                                            const float* __restrict__ pw2,
                                            _Float16* __restrict__ aw1h,
                                            _Float16* __restrict__ aw2h,
                                            _Float16* __restrict__ pw2h) {
    int i = blockIdx.x * 256 + threadIdx.x;
    if (i < 65536) { aw1h[i] = (_Float16)aw1[i]; aw2h[i] = (_Float16)aw2[i]; }
    if (i < 16384) { pw2h[i] = (_Float16)pw2[i]; }
}

// ------- distance GEMM (f16 hi/lo refs -- REQUIRED: f16-only refs flipped
// neighbors, r13 absmax 1.41) + bitonic top-16. 512 thr = 8 waves = 128
// queries/block sharing each staged ref tile.
__global__ __launch_bounds__(512, 4) void score_knn(const _Float16* __restrict__ featH,
                                                    const _Float16* __restrict__ featL,
                                                    const float* __restrict__ r2g,
                                                    unsigned* __restrict__ partial) {
    __shared__ __align__(16) char sbuf[65536];   // 2 x (smH 16K | smL 16K)
    __shared__ float sr2[CSIZE];

    const int tid = threadIdx.x;
    const int lane = tid & 63, wave = tid >> 6;   // 8 waves
    const int l15 = lane & 15, l4 = lane >> 4;
    const int chunk = blockIdx.x, qt = blockIdx.y, b = blockIdx.z;
    const int nq = qt * QPB + wave * 16 + l15;
    const int m0 = chunk * CSIZE;

    sr2[tid] = r2g[b * MPTS + m0 + tid];   // 512 == CSIZE

    half8 qh[8], ql[8];
    {
        const _Float16* qb = featH + ((size_t)b * MPTS + nq) * CDIM + l4 * 8;
        const _Float16* qL = featL + ((size_t)b * MPTS + nq) * CDIM + l4 * 8;
#pragma unroll
        for (int ks = 0; ks < 8; ks++) {
            qh[ks] = *(const half8*)(qb + ks * 32);
            ql[ks] = *(const half8*)(qL + ks * 32);
        }
    }

    // step-invariant LDS read addresses (octet o = ks*4+l4; XOR key = ks&7)
    int adr[8];
#pragma unroll
    for (int ks = 0; ks < 8; ks++)
        adr[ks] = (ks * 4 + l4) * 512 + ((l15 * 16) ^ ((ks & 7) << 4));

    // staging: 2 16B-units per thread: row = tid>>4 (0..31), o = 2*(tid&15)+j
    const int srow = tid >> 4;
    const int o0 = 2 * (tid & 15);
    int wadr[2];
#pragma unroll
    for (int j = 0; j < 2; j++) {
        int o = o0 + j;
        wadr[j] = o * 512 + ((srow * 16) ^ (((o >> 2) & 7) << 4));
    }
    const char* gH = (const char*)(featH + ((size_t)b * MPTS + m0 + srow) * CDIM) + o0 * 16;
    const char* gL = (const char*)(featL + ((size_t)b * MPTS + m0 + srow) * CDIM) + o0 * 16;

    unsigned td[16];
#pragma unroll
    for (int i = 0; i < 16; i++) td[i] = 0xFFFFFFFFu;

    half8 pH[2], pL[2];
#pragma unroll
    for (int j = 0; j < 2; j++) {
        pH[j] = *(const half8*)(gH + j * 16);
        pL[j] = *(const half8*)(gL + j * 16);
    }
    gH += 32 * CDIM * 2;
    gL += 32 * CDIM * 2;

    for (int s = 0; s < NSTEPS; ++s) {
        char* buf = sbuf + (s & 1) * 32768;
#pragma unroll
        for (int j = 0; j < 2; j++) {
            *(half8*)(buf + wadr[j])         = pH[j];
            *(half8*)(buf + 16384 + wadr[j]) = pL[j];
        }
        __syncthreads();

        if (s < NSTEPS - 1) {
#pragma unroll
            for (int j = 0; j < 2; j++) {
                pH[j] = *(const half8*)(gH + j * 16);
                pL[j] = *(const half8*)(gL + j * 16);
            }
            gH += 32 * CDIM * 2;
            gL += 32 * CDIM * 2;
        }

        unsigned kk[8];
#pragma unroll
        for (int sub = 0; sub < 2; ++sub) {
            f32x4 a0 = {0.f, 0.f, 0.f, 0.f};
            f32x4 a1 = {0.f, 0.f, 0.f, 0.f};
            f32x4 a2 = {0.f, 0.f, 0.f, 0.f};
#pragma unroll
            for (int ks = 0; ks < 8; ks++) {
                half8 ah = *(const half8*)(buf + adr[ks] + sub * 256);
                half8 al = *(const half8*)(buf + 16384 + adr[ks] + sub * 256);
                a0 = __builtin_amdgcn_mfma_f32_16x16x32_f16(ah, qh[ks], a0, 0, 0, 0);
                a1 = __builtin_amdgcn_mfma_f32_16x16x32_f16(ah, ql[ks], a1, 0, 0, 0);
                a2 = __builtin_amdgcn_mfma_f32_16x16x32_f16(al, qh[ks], a2, 0, 0, 0);
            }
            float4 s4 = *(const float4*)(sr2 + s * 32 + sub * 16 + 4 * l4);
            const float sv[4] = {s4.x, s4.y, s4.z, s4.w};
            const int mloc0 = s * 32 + sub * 16 + 4 * l4;
#pragma unroll
            for (int r = 0; r < 4; r++) {
                float d = fmaxf(sv[r] - 2.f * (a0[r] + a1[r] + a2[r]), 0.f);
                unsigned dq = (unsigned)(d * 4096.f);
                dq = dq > 0x7FFFF0u ? 0x7FFFF0u : dq;
                kk[sub * 4 + r] = (dq << 9) | (unsigned)(mloc0 + r);
            }
        }
        CEA(0,1) CEA(2,3) CEA(4,5) CEA(6,7)
        CEA(0,2) CEA(1,3) CEA(4,6) CEA(5,7)
        CEA(1,2) CEA(5,6) CEA(0,4) CEA(3,7)
        CEA(1,5) CEA(2,6)
        CEA(1,4) CEA(3,6)
        CEA(2,4) CEA(3,5)
        CEA(3,4)
#pragma unroll
        for (int i = 0; i < 8; i++) td[i] = td[i] < kk[i] ? td[i] : kk[i];
        RESORT16
    }

    // merge the 4 per-lane sorted lists via xor-shuffle bitonic merges
#pragma unroll
    for (int rr = 0; rr < 2; rr++) {
        const int dx = 16 << rr;
        unsigned ot[16];
#pragma unroll
        for (int e = 0; e < 16; e++) ot[e] = __shfl_xor(td[e], dx);
#pragma unroll
        for (int e = 0; e < 16; e++) {
            unsigned o = ot[15 - e];
            td[e] = td[e] < o ? td[e] : o;
        }
        RESORT16
    }
    if (l4 == 0) {
        const size_t qrow = (size_t)b * NPTS + qt * QPB + wave * 16 + l15;
#pragma unroll
        for (int e = 0; e < 16; e++)
            partial[(size_t)(chunk * 16 + e) * (NB * NPTS) + qrow] = td[e];
    }
}

// ------- final merge: NCHUNK x 16 keys -> top-16 indices per row
__global__ __launch_bounds__(256) void merge16(const unsigned* __restrict__ partial,
                                               int* __restrict__ idxout) {
    const int row = blockIdx.x * 256 + threadIdx.x;
    unsigned long long td[16];
#pragma unroll
    for (int i = 0; i < 16; i++) td[i] = 0x8000000000ull + (unsigned long long)i;
    unsigned long long curmax = 0x800000000Full;
    for (int e = 0; e < NCHUNK * 16; e++) {
        unsigned k = partial[(size_t)e * (NB * NPTS) + row];
        unsigned long long k64 =
            (((unsigned long long)(k >> 9)) << 12) |
            (unsigned long long)((unsigned)((e >> 4) << 9) | (k & 0x1FFu));
        if (k64 < curmax) {
#pragma unroll
            for (int i_ = 0; i_ < 16; i_++) td[i_] = (td[i_] == curmax) ? k64 : td[i_];
            unsigned long long nm_ = td[0];
#pragma unroll
            for (int i_ = 1; i_ < 16; i_++) nm_ = td[i_] > nm_ ? td[i_] : nm_;
            curmax = nm_;
        }
    }
#pragma unroll
    for (int e = 0; e < 16; e++) idxout[row * 16 + e] = (int)(td[e] & 0xFFFull);
}

// ------- fused MLP chain on f16 MFMA (round-11 fused_mlp6 verbatim -- the
// no-spill register schedule: fmv/fnv die at phase 4, weights one rt at a
// time, gfa in epilogue).
__global__ __launch_bounds__(512, 4) void fused_mlp6(
    const float* __restrict__ pcd, const float* __restrict__ pcddb,
    const _Float16* __restrict__ featH, const int* __restrict__ knn,
    const float* __restrict__ pw1, const float* __restrict__ pb1,
    const float* __restrict__ pg, const float* __restrict__ pbe,
    const float* __restrict__ pm, const float* __restrict__ pv,
    const _Float16* __restrict__ pw2h, const float* __restrict__ pb2,
    const _Float16* __restrict__ aw1h, const float* __restrict__ ab1,
    const float* __restrict__ ag, const float* __restrict__ abe,
    const float* __restrict__ am, const float* __restrict__ av,
    const _Float16* __restrict__ aw2h,
    float* __restrict__ out) {
    __shared__ __align__(16) _Float16 xbuf[COLS * 256];   // pe -> x -> a1
    __shared__ __align__(16) _Float16 hbuf[COLS * 64];
    __shared__ __align__(16) float pr[3][COLS];
    __shared__ int sidx[COLS];
    __shared__ __align__(16) float ainv[256], ash2[256], pinv[64], psh[64];

    const int tid = threadIdx.x;
    const int lane = tid & 63, wave = tid >> 6;
    const int l15 = lane & 15, l4 = lane >> 4;
    const int blk = blockIdx.x;
    const int b = blk >> 9;
    const int n0 = (blk & 511) * 4;
    const int R0 = wave * 32;

    // ---- phase 0: consts + sidx; preload pw2 fragments
    if (tid < COLS) {
        sidx[tid] = knn[(size_t)(b * NPTS + n0 + (tid >> 4)) * KNN + (tid & 15)];
    } else if (tid < COLS + 256) {
        int c = tid - COLS;
        float inv = ag[c] / sqrtf(av[c] + 1e-5f);
        ainv[c] = inv;
        ash2[c] = abe[c] - am[c] * inv + ab1[c] * inv;
    } else if (tid < COLS + 256 + 64) {
        int o = tid - COLS - 256;
        float inv = pg[o] / sqrtf(pv[o] + 1e-5f);
        pinv[o] = inv;
        psh[o] = pbe[o] - pm[o] * inv;
    }
    half8 wp[2][2];
#pragma unroll
    for (int rt = 0; rt < 2; rt++)
#pragma unroll
        for (int ks = 0; ks < 2; ks++)
            wp[rt][ks] = *(const half8*)(pw2h + (size_t)(R0 + rt * 16 + l15) * 64 +
                                         ks * 32 + l4 * 8);
    __syncthreads();

    // ---- phase 1: pr gather + fm/fn prefetch (T14)
    if (tid < 3 * COLS) {
        int c = tid >> 6, col = tid & 63;
        int m = sidx[col];
        const float* pc = pcd + ((size_t)b * 3 + c) * NPTS;
        const float* px = pcddb + ((size_t)b * 3 + c) * NPTS;
        float gp = (m < NPTS) ? pc[m] : px[m - NPTS];
        pr[c][col] = pc[n0 + (col >> 4)] - gp;
    }
    const int colx = tid & 63;
    const int c0x = (tid >> 6) * 32;
    half8 fmv[4], fnv[4];
    {
        const _Float16* fmp = featH + ((size_t)b * MPTS + sidx[colx]) * CDIM + c0x;
        const _Float16* fnp = featH + ((size_t)b * MPTS + n0 + (colx >> 4)) * CDIM + c0x;
#pragma unroll
        for (int j = 0; j < 4; j++) {
            fmv[j] = *(const half8*)(fmp + j * 8);
            fnv[j] = *(const half8*)(fnp + j * 8);
        }
    }
    __syncthreads();

    // ---- phase 2: h = relu(bn(pw1 @ pos_rel)) -> hbuf [col][64]
    {
        int col = tid >> 3, o0 = (tid & 7) * 8;
        float x0 = pr[0][col], x1 = pr[1][col], x2 = pr[2][col];
        half8 hv;
#pragma unroll
        for (int i = 0; i < 8; i++) {
            int o = o0 + i;
            float v = pw1[o * 3] * x0 + pw1[o * 3 + 1] * x1 + pw1[o * 3 + 2] * x2 + pb1[o];
            v = fmaxf(v * pinv[o] + psh[o], 0.f);
            hv[i] = (_Float16)v;
        }
        *(half8*)((char*)hbuf + swz128(col, o0 * 2)) = hv;
    }
    __syncthreads();

    // ---- phase 3: pe GEMM + epilogue -> xbuf (as pe) AND registers pe4
    f32x4 acc[2][4];
#pragma unroll
    for (int rt = 0; rt < 2; rt++)
#pragma unroll
        for (int ct = 0; ct < 4; ct++) acc[rt][ct] = (f32x4){0.f, 0.f, 0.f, 0.f};
#pragma unroll
    for (int ks = 0; ks < 2; ks++) {
        int k0 = ks * 32 + l4 * 8;
#pragma unroll
        for (int ct = 0; ct < 4; ct++) {
            half8 bb = *(const half8*)((char*)hbuf + swz128(ct * 16 + l15, k0 * 2));
            acc[0][ct] = __builtin_amdgcn_mfma_f32_16x16x32_f16(wp[0][ks], bb, acc[0][ct], 0, 0, 0);
            acc[1][ct] = __builtin_amdgcn_mfma_f32_16x16x32_f16(wp[1][ks], bb, acc[1][ct], 0, 0, 0);
        }
    }
    half4 pe4[2][4];
#pragma unroll
    for (int rt = 0; rt < 2; rt++) {
        int cb = R0 + rt * 16 + 4 * l4;
        float4 pb = *(const float4*)(pb2 + cb);
        float pbv[4] = {pb.x, pb.y, pb.z, pb.w};
#pragma unroll
        for (int ct = 0; ct < 4; ct++) {
            int col = ct * 16 + l15;
            half4 p4;
#pragma unroll
            for (int r = 0; r < 4; r++) p4[r] = (_Float16)(acc[rt][ct][r] + pbv[r]);
            pe4[rt][ct] = p4;
            *(half4*)((char*)xbuf + swzS(col, cb * 2)) = p4;
        }
    }
    __syncthreads();

    // ---- phase 4: x = fn - fm + pe, in-place on xbuf; preload aw1 rt0 only
#pragma unroll
    for (int j = 0; j < 4; j++) {
        int c = c0x + j * 8;
        half8 vp = *(const half8*)((char*)xbuf + swzS(colx, c * 2));
        half8 xv = fnv[j] - fmv[j] + vp;
        *(half8*)((char*)xbuf + swzS(colx, c * 2)) = xv;
    }
    half8 wa[8];
#pragma unroll
    for (int ks = 0; ks < 8; ks++)
        wa[ks] = *(const half8*)(aw1h + (size_t)(R0 + l15) * 256 + ks * 32 + l4 * 8);
    __syncthreads();

    // ---- phase 5: GEMM1, one rt at a time (32 weight regs peak)
#pragma unroll
    for (int rt = 0; rt < 2; rt++)
#pragma unroll
        for (int ct = 0; ct < 4; ct++) acc[rt][ct] = (f32x4){0.f, 0.f, 0.f, 0.f};
#pragma unroll
    for (int ks = 0; ks < 8; ks++) {
        int k0 = ks * 32 + l4 * 8;
#pragma unroll
        for (int ct = 0; ct < 4; ct++) {
            half8 bb = *(const half8*)((char*)xbuf + swzS(ct * 16 + l15, k0 * 2));
            acc[0][ct] = __builtin_amdgcn_mfma_f32_16x16x32_f16(wa[ks], bb, acc[0][ct], 0, 0, 0);
        }
    }
#pragma unroll
    for (int ks = 0; ks < 8; ks++)
        wa[ks] = *(const half8*)(aw1h + (size_t)(R0 + 16 + l15) * 256 + ks * 32 + l4 * 8);
#pragma unroll
    for (int ks = 0; ks < 8; ks++) {
        int k0 = ks * 32 + l4 * 8;
#pragma unroll
        for (int ct = 0; ct < 4; ct++) {
            half8 bb = *(const half8*)((char*)xbuf + swzS(ct * 16 + l15, k0 * 2));
            acc[1][ct] = __builtin_amdgcn_mfma_f32_16x16x32_f16(wa[ks], bb, acc[1][ct], 0, 0, 0);
        }
    }
    __syncthreads();

    // ---- phase 6: a1 = relu(bn(.)) -> xbuf; preload aw2 rt0
#pragma unroll
    for (int rt = 0; rt < 2; rt++) {
        int cb = R0 + rt * 16 + 4 * l4;
        float4 iv = *(const float4*)(&ainv[cb]);
        float4 sh = *(const float4*)(&ash2[cb]);
        float ivv[4] = {iv.x, iv.y, iv.z, iv.w};
        float shv[4] = {sh.x, sh.y, sh.z, sh.w};
#pragma unroll
        for (int ct = 0; ct < 4; ct++) {
            int col = ct * 16 + l15;
            half4 h4;
#pragma unroll
            for (int r = 0; r < 4; r++)
                h4[r] = (_Float16)fmaxf(acc[rt][ct][r] * ivv[r] + shv[r], 0.f);
            *(half4*)((char*)xbuf + swzS(col, cb * 2)) = h4;
        }
    }
#pragma unroll
    for (int ks = 0; ks < 8; ks++)
        wa[ks] = *(const half8*)(aw2h + (size_t)(R0 + l15) * 256 + ks * 32 + l4 * 8);
    __syncthreads();

    // ---- phase 7: GEMM2, one rt at a time
#pragma unroll
    for (int rt = 0; rt < 2; rt++)
#pragma unroll
        for (int ct = 0; ct < 4; ct++) acc[rt][ct] = (f32x4){0.f, 0.f, 0.f, 0.f};
#pragma unroll
    for (int ks = 0; ks < 8; ks++) {
        int k0 = ks * 32 + l4 * 8;
#pragma unroll
        for (int ct = 0; ct < 4; ct++) {
            half8 bb = *(const half8*)((char*)xbuf + swzS(ct * 16 + l15, k0 * 2));
            acc[0][ct] = __builtin_amdgcn_mfma_f32_16x16x32_f16(wa[ks], bb, acc[0][ct], 0, 0, 0);
        }
    }
#pragma unroll
    for (int ks = 0; ks < 8; ks++)
        wa[ks] = *(const half8*)(aw2h + (size_t)(R0 + 16 + l15) * 256 + ks * 32 + l4 * 8);
#pragma unroll
    for (int ks = 0; ks < 8; ks++) {
        int k0 = ks * 32 + l4 * 8;
#pragma unroll
        for (int ct = 0; ct < 4; ct++) {
            half8 bb = *(const half8*)((char*)xbuf + swzS(ct * 16 + l15, k0 * 2));
            acc[1][ct] = __builtin_amdgcn_mfma_f32_16x16x32_f16(wa[ks], bb, acc[1][ct], 0, 0, 0);
        }
    }

    // ---- epilogue: gfa gather here (weights dead), DPP softmax, stores
#pragma unroll
    for (int rt = 0; rt < 2; rt++) {
        int cb = R0 + rt * 16 + 4 * l4;
        half4 gfa[4];
#pragma unroll
        for (int ct = 0; ct < 4; ct++)
            gfa[ct] = *(const half4*)(featH +
                ((size_t)b * MPTS + sidx[ct * 16 + l15]) * CDIM + cb);
#pragma unroll
        for (int ct = 0; ct < 4; ct++) {
            float oo[4], ss[4];
#pragma unroll
            for (int r = 0; r < 4; r++) {
                float v = acc[rt][ct][r];
                v = fminf(fmaxf(v, -60.f), 60.f);
                float e = __expf(v);
                float sv = (float)gfa[ct][r] + (float)pe4[rt][ct][r];
                ss[r] = sum16(e);
                oo[r] = sum16(e * sv);
            }
            if (l15 < 4) {
                float o = l15 == 0 ? oo[0] : l15 == 1 ? oo[1] : l15 == 2 ? oo[2] : oo[3];
                float s = l15 == 0 ? ss[0] : l15 == 1 ? ss[1] : l15 == 2 ? ss[2] : ss[3];
                out[((size_t)b * CDIM + cb + l15) * NPTS + n0 + ct] =
                    o * __builtin_amdgcn_rcpf(s);
            }
        }
    }
}

// ------------------------------------------------------------------- launch
extern "C" void kernel_launch(void* const* d_in, const int* in_sizes, int n_in,
                              void* d_out, int out_size, void* d_ws, size_t ws_size,
                              hipStream_t stream) {
    const float* pcd    = (const float*)d_in[0];
    const float* feat   = (const float*)d_in[1];
    const float* pcddb  = (const float*)d_in[2];
    const float* featdb = (const float*)d_in[3];
    const float* pw1 = (const float*)d_in[4];
    const float* pb1 = (const float*)d_in[5];
    const float* pg  = (const float*)d_in[6];
    const float* pbe = (const float*)d_in[7];
    const float* pm  = (const float*)d_in[8];
    const float* pv  = (const float*)d_in[9];
    const float* pw2 = (const float*)d_in[10];
    const float* pb2 = (const float*)d_in[11];
    const float* aw1 = (const float*)d_in[12];
    const float* ab1 = (const float*)d_in[13];
    const float* ag  = (const float*)d_in[14];
    const float* abe = (const float*)d_in[15];
    const float* am  = (const float*)d_in[16];
    const float* av  = (const float*)d_in[17];
    const float* aw2 = (const float*)d_in[18];
    // d_in[19] = ab2: constant over k -> cancels in softmax, unused
    float* out = (float*)d_out;

    char* ws = (char*)d_ws;
    _Float16* featH   = (_Float16*)(ws);               // 8 MB
    _Float16* featL   = (_Float16*)(ws + 8388608);     // 8 MB
    float*    ws_r2   = (float*)(ws + 16777216);       // 64 KB
    unsigned* partial = (unsigned*)(ws + 16842752);    // 4 MB
    int*      ws_idx  = (int*)(ws + 21037056);         // 512 KB
    _Float16* aw1h    = (_Float16*)(ws + 21561344);    // 128 KB
    _Float16* aw2h    = (_Float16*)(ws + 21692416);    // 128 KB
    _Float16* pw2h    = (_Float16*)(ws + 21823488);    // 32 KB

    wcvt<<<256, 256, 0, stream>>>(aw1, aw2, pw2, aw1h, aw2h, pw2h);
    tposeHL2<<<dim3(MPTS / 32, NB), 256, 0, stream>>>(feat, featdb, featH, featL, ws_r2);
    score_knn<<<dim3(NCHUNK, NPTS / QPB, NB), 512, 0, stream>>>(featH, featL, ws_r2, partial);
    merge16<<<NB * NPTS / 256, 256, 0, stream>>>(partial, ws_idx);
    fused_mlp6<<<NB * (NPTS / 4), 512, 0, stream>>>(
        pcd, pcddb, featH, ws_idx,
        pw1, pb1, pg, pbe, pm, pv, pw2h, pb2,
        aw1h, ab1, ag, abe, am, av, aw2h, out);
}

// Round 15
// 266.943 us; speedup vs baseline: 1.0491x; 1.0204x over previous
//
#include <hip/hip_runtime.h>
#include <float.h>

#define CDIM 256
#define NPTS 2048
#define MPTS 4096
#define NB   4
#define KNN  16
#define COLS 64     // fused_mlp: NPB(4) * KNN
#define NCHUNK 8
#define CSIZE  512
#define NSTEPS 16
#define QPB   256   // score_knn queries per block (16 waves)

typedef _Float16 half8 __attribute__((ext_vector_type(8)));
typedef _Float16 half4 __attribute__((ext_vector_type(4)));
typedef float    f32x4 __attribute__((ext_vector_type(4)));

// swizzled byte offsets: row stride 512B / 128B
__device__ __forceinline__ int swzS(int row, int byte) {
    return row * 512 + (byte ^ ((row & 7) << 4));
}
__device__ __forceinline__ int swz128(int row, int byte) {
    return row * 128 + (byte ^ ((row & 7) << 4));
}

// 16-lane (DPP row) sum via rotations; every lane ends with the total.
__device__ __forceinline__ float sum16(float v) {
    v += __uint_as_float(__builtin_amdgcn_update_dpp(0, __float_as_uint(v), 0x128, 0xF, 0xF, true));
    v += __uint_as_float(__builtin_amdgcn_update_dpp(0, __float_as_uint(v), 0x124, 0xF, 0xF, true));
    v += __uint_as_float(__builtin_amdgcn_update_dpp(0, __float_as_uint(v), 0x122, 0xF, 0xF, true));
    v += __uint_as_float(__builtin_amdgcn_update_dpp(0, __float_as_uint(v), 0x121, 0xF, 0xF, true));
    return v;
}

// compare-exchange: kk ascending
#define CEA(x, y)                                                               \
    { unsigned lo_ = kk[x] < kk[y] ? kk[x] : kk[y];                             \
      unsigned hi_ = kk[x] < kk[y] ? kk[y] : kk[x];                             \
      kk[x] = lo_; kk[y] = hi_; }
// compare-exchange: td descending (max to lower index)
#define CED(x, y)                                                               \
    { unsigned hi_ = td[x] > td[y] ? td[x] : td[y];                             \
      unsigned lo_ = td[x] > td[y] ? td[y] : td[x];                             \
      td[x] = hi_; td[y] = lo_; }
// bitonic-16 -> sorted descending (spans 8,4,2,1)
#define RESORT16                                                                \
    CED(0,8) CED(1,9) CED(2,10) CED(3,11) CED(4,12) CED(5,13) CED(6,14) CED(7,15) \
    CED(0,4) CED(1,5) CED(2,6) CED(3,7) CED(8,12) CED(9,13) CED(10,14) CED(11,15) \
    CED(0,2) CED(1,3) CED(4,6) CED(5,7) CED(8,10) CED(9,11) CED(12,14) CED(13,15) \
    CED(0,1) CED(2,3) CED(4,5) CED(6,7) CED(8,9) CED(10,11) CED(12,13) CED(14,15)

// ------- (B,C,M) fp32 -> featH/featL (B,M,C) f16 hi/lo + r2, tiled & coalesced
__global__ __launch_bounds__(256) void tposeHL2(const float* __restrict__ feat,
                                                const float* __restrict__ featdb,
                                                _Float16* __restrict__ featH,
                                                _Float16* __restrict__ featL,
                                                float* __restrict__ r2) {
    __shared__ float red[8][33];
    const int b = blockIdx.y;
    const int mt = blockIdx.x;
    const int m = threadIdx.x & 31;
    const int cp = threadIdx.x >> 5;
    const int mg = mt * 32 + m;
    const float* src = (mg < NPTS) ? (feat + (size_t)b * CDIM * NPTS + mg)
                                   : (featdb + (size_t)b * CDIM * NPTS + (mg - NPTS));
    const int c0 = cp * 32;
    float acc = 0.f;
    half8 hh[4], ll[4];
#pragma unroll
    for (int i = 0; i < 32; i++) {
        float v = src[(size_t)(c0 + i) * NPTS];
        acc += v * v;
        _Float16 h = (_Float16)v;
        hh[i >> 3][i & 7] = h;
        ll[i >> 3][i & 7] = (_Float16)(v - (float)h);
    }
    _Float16* dh = featH + ((size_t)b * MPTS + mg) * CDIM + c0;
    _Float16* dl = featL + ((size_t)b * MPTS + mg) * CDIM + c0;
#pragma unroll
    for (int i = 0; i < 4; i++) {
        *(half8*)(dh + i * 8) = hh[i];
        *(half8*)(dl + i * 8) = ll[i];
    }
    red[cp][m] = acc;
    __syncthreads();
    if (threadIdx.x < 32) {
        float s = 0.f;
#pragma unroll
        for (int j = 0; j < 8; j++) s += red[j][threadIdx.x];
        r2[b * MPTS + mt * 32 + threadIdx.x] = s;
    }
}

// ------- weights fp32 -> f16
__global__ __launch_bounds__(256) void wcvt(const float* __restrict__ aw1,
                                            const float* __restrict__ aw2,
                                            const float* __restrict__ pw2,
                                            _Float16* __restrict__ aw1h,
                                            _Float16* __restrict__ aw2h,
                                            _Float16* __restrict__ pw2h) {
    int i = blockIdx.x * 256 + threadIdx.x;
    if (i < 65536) { aw1h[i] = (_Float16)aw1[i]; aw2h[i] = (_Float16)aw2[i]; }
    if (i < 16384) { pw2h[i] = (_Float16)pw2[i]; }
}

// ------- distance GEMM (f16 hi/lo refs -- REQUIRED, r13 lesson) + bitonic
// top-16. QPB=256: 1024 thr = 16 waves share each staged ref tile -- halves
// the LLC-bound ref traffic (268 -> 134 MB) that dominates this kernel.
__global__ __launch_bounds__(1024, 2) void score_knn(const _Float16* __restrict__ featH,
                                                     const _Float16* __restrict__ featL,
                                                     const float* __restrict__ r2g,
                                                     unsigned* __restrict__ partial) {
    __shared__ __align__(16) char sbuf[65536];   // 2 x (smH 16K | smL 16K)
    __shared__ float sr2[CSIZE];

    const int tid = threadIdx.x;
    const int lane = tid & 63, wave = tid >> 6;   // 16 waves
    const int l15 = lane & 15, l4 = lane >> 4;
    const int chunk = blockIdx.x, qt = blockIdx.y, b = blockIdx.z;
    const int nq = qt * QPB + wave * 16 + l15;
    const int m0 = chunk * CSIZE;

    if (tid < CSIZE) sr2[tid] = r2g[b * MPTS + m0 + tid];

    half8 qh[8], ql[8];
    {
        const _Float16* qb = featH + ((size_t)b * MPTS + nq) * CDIM + l4 * 8;
        const _Float16* qL = featL + ((size_t)b * MPTS + nq) * CDIM + l4 * 8;
#pragma unroll
        for (int ks = 0; ks < 8; ks++) {
            qh[ks] = *(const half8*)(qb + ks * 32);
            ql[ks] = *(const half8*)(qL + ks * 32);
        }
    }

    // step-invariant LDS read addresses (octet o = ks*4+l4; XOR key = ks&7)
    int adr[8];
#pragma unroll
    for (int ks = 0; ks < 8; ks++)
        adr[ks] = (ks * 4 + l4) * 512 + ((l15 * 16) ^ ((ks & 7) << 4));

    // staging: 1 16B-unit per thread per buffer: row = tid>>5, octet = tid&31
    const int srow = tid >> 5;
    const int oo = tid & 31;
    const int wadr = oo * 512 + ((srow * 16) ^ (((oo >> 2) & 7) << 4));
    const char* gH = (const char*)(featH + ((size_t)b * MPTS + m0 + srow) * CDIM) + oo * 16;
    const char* gL = (const char*)(featL + ((size_t)b * MPTS + m0 + srow) * CDIM) + oo * 16;

    unsigned td[16];
#pragma unroll
    for (int i = 0; i < 16; i++) td[i] = 0xFFFFFFFFu;

    half8 pH = *(const half8*)gH;
    half8 pL = *(const half8*)gL;
    gH += 32 * CDIM * 2;
    gL += 32 * CDIM * 2;

    for (int s = 0; s < NSTEPS; ++s) {
        char* buf = sbuf + (s & 1) * 32768;
        *(half8*)(buf + wadr)         = pH;
        *(half8*)(buf + 16384 + wadr) = pL;
        __syncthreads();

        if (s < NSTEPS - 1) {
            pH = *(const half8*)gH;
            pL = *(const half8*)gL;
            gH += 32 * CDIM * 2;
            gL += 32 * CDIM * 2;
        }

        unsigned kk[8];
#pragma unroll
        for (int sub = 0; sub < 2; ++sub) {
            f32x4 a0 = {0.f, 0.f, 0.f, 0.f};
            f32x4 a1 = {0.f, 0.f, 0.f, 0.f};
            f32x4 a2 = {0.f, 0.f, 0.f, 0.f};
#pragma unroll
            for (int ks = 0; ks < 8; ks++) {
                half8 ah = *(const half8*)(buf + adr[ks] + sub * 256);
                half8 al = *(const half8*)(buf + 16384 + adr[ks] + sub * 256);
                a0 = __builtin_amdgcn_mfma_f32_16x16x32_f16(ah, qh[ks], a0, 0, 0, 0);
                a1 = __builtin_amdgcn_mfma_f32_16x16x32_f16(ah, ql[ks], a1, 0, 0, 0);
                a2 = __builtin_amdgcn_mfma_f32_16x16x32_f16(al, qh[ks], a2, 0, 0, 0);
            }
            float4 s4 = *(const float4*)(sr2 + s * 32 + sub * 16 + 4 * l4);
            const float sv[4] = {s4.x, s4.y, s4.z, s4.w};
            const int mloc0 = s * 32 + sub * 16 + 4 * l4;
#pragma unroll
            for (int r = 0; r < 4; r++) {
                float d = fmaxf(sv[r] - 2.f * (a0[r] + a1[r] + a2[r]), 0.f);
                unsigned dq = (unsigned)(d * 4096.f);
                dq = dq > 0x7FFFF0u ? 0x7FFFF0u : dq;
                kk[sub * 4 + r] = (dq << 9) | (unsigned)(mloc0 + r);
            }
        }
        CEA(0,1) CEA(2,3) CEA(4,5) CEA(6,7)
        CEA(0,2) CEA(1,3) CEA(4,6) CEA(5,7)
        CEA(1,2) CEA(5,6) CEA(0,4) CEA(3,7)
        CEA(1,5) CEA(2,6)
        CEA(1,4) CEA(3,6)
        CEA(2,4) CEA(3,5)
        CEA(3,4)
#pragma unroll
        for (int i = 0; i < 8; i++) td[i] = td[i] < kk[i] ? td[i] : kk[i];
        RESORT16
    }

    // merge the 4 per-lane sorted lists via xor-shuffle bitonic merges
#pragma unroll
    for (int rr = 0; rr < 2; rr++) {
        const int dx = 16 << rr;
        unsigned ot[16];
#pragma unroll
        for (int e = 0; e < 16; e++) ot[e] = __shfl_xor(td[e], dx);
#pragma unroll
        for (int e = 0; e < 16; e++) {
            unsigned o = ot[15 - e];
            td[e] = td[e] < o ? td[e] : o;
        }
        RESORT16
    }
    if (l4 == 0) {
        const size_t qrow = (size_t)b * NPTS + qt * QPB + wave * 16 + l15;
#pragma unroll
        for (int e = 0; e < 16; e++)
            partial[(size_t)(chunk * 16 + e) * (NB * NPTS) + qrow] = td[e];
    }
}

// ------- final merge: NCHUNK x 16 keys -> top-16 indices per row
__global__ __launch_bounds__(256) void merge16(const unsigned* __restrict__ partial,
                                               int* __restrict__ idxout) {
    const int row = blockIdx.x * 256 + threadIdx.x;
    unsigned long long td[16];
#pragma unroll
    for (int i = 0; i < 16; i++) td[i] = 0x8000000000ull + (unsigned long long)i;
    unsigned long long curmax = 0x800000000Full;
    for (int e = 0; e < NCHUNK * 16; e++) {
        unsigned k = partial[(size_t)e * (NB * NPTS) + row];
        unsigned long long k64 =
            (((unsigned long long)(k >> 9)) << 12) |
            (unsigned long long)((unsigned)((e >> 4) << 9) | (k & 0x1FFu));
        if (k64 < curmax) {
#pragma unroll
            for (int i_ = 0; i_ < 16; i_++) td[i_] = (td[i_] == curmax) ? k64 : td[i_];
            unsigned long long nm_ = td[0];
#pragma unroll
            for (int i_ = 1; i_ < 16; i_++) nm_ = td[i_] > nm_ ? td[i_] : nm_;
            curmax = nm_;
        }
    }
#pragma unroll
    for (int e = 0; e < 16; e++) idxout[row * 16 + e] = (int)(td[e] & 0xFFFull);
}

// ------- fused MLP chain on f16 MFMA (round-14-passing fused_mlp6 verbatim)
__global__ __launch_bounds__(512, 4) void fused_mlp6(
    const float* __restrict__ pcd, const float* __restrict__ pcddb,
    const _Float16* __restrict__ featH, const int* __restrict__ knn,
    const float* __restrict__ pw1, const float* __restrict__ pb1,
    const float* __restrict__ pg, const float* __restrict__ pbe,
    const float* __restrict__ pm, const float* __restrict__ pv,
    const _Float16* __restrict__ pw2h, const float* __restrict__ pb2,
    const _Float16* __restrict__ aw1h, const float* __restrict__ ab1,
    const float* __restrict__ ag, const float* __restrict__ abe,
    const float* __restrict__ am, const float* __restrict__ av,
    const _Float16* __restrict__ aw2h,
    float* __restrict__ out) {
    __shared__ __align__(16) _Float16 xbuf[COLS * 256];   // pe -> x -> a1
    __shared__ __align__(16) _Float16 hbuf[COLS * 64];
    __shared__ __align__(16) float pr[3][COLS];
    __shared__ int sidx[COLS];
    __shared__ __align__(16) float ainv[256], ash2[256], pinv[64], psh[64];

    const int tid = threadIdx.x;
    const int lane = tid & 63, wave = tid >> 6;
    const int l15 = lane & 15, l4 = lane >> 4;
    const int blk = blockIdx.x;
    const int b = blk >> 9;
    const int n0 = (blk & 511) * 4;
    const int R0 = wave * 32;

    // ---- phase 0: consts + sidx; preload pw2 fragments
    if (tid < COLS) {
        sidx[tid] = knn[(size_t)(b * NPTS + n0 + (tid >> 4)) * KNN + (tid & 15)];
    } else if (tid < COLS + 256) {
        int c = tid - COLS;
        float inv = ag[c] / sqrtf(av[c] + 1e-5f);
        ainv[c] = inv;
        ash2[c] = abe[c] - am[c] * inv + ab1[c] * inv;
    } else if (tid < COLS + 256 + 64) {
        int o = tid - COLS - 256;
        float inv = pg[o] / sqrtf(pv[o] + 1e-5f);
        pinv[o] = inv;
        psh[o] = pbe[o] - pm[o] * inv;
    }
    half8 wp[2][2];
#pragma unroll
    for (int rt = 0; rt < 2; rt++)
#pragma unroll
        for (int ks = 0; ks < 2; ks++)
            wp[rt][ks] = *(const half8*)(pw2h + (size_t)(R0 + rt * 16 + l15) * 64 +
                                         ks * 32 + l4 * 8);
    __syncthreads();

    // ---- phase 1: pr gather + fm/fn prefetch (T14)
    if (tid < 3 * COLS) {
        int c = tid >> 6, col = tid & 63;
        int m = sidx[col];
        const float* pc = pcd + ((size_t)b * 3 + c) * NPTS;
        const float* px = pcddb + ((size_t)b * 3 + c) * NPTS;
        float gp = (m < NPTS) ? pc[m] : px[m - NPTS];
        pr[c][col] = pc[n0 + (col >> 4)] - gp;
    }
    const int colx = tid & 63;
    const int c0x = (tid >> 6) * 32;
    half8 fmv[4], fnv[4];
    {
        const _Float16* fmp = featH + ((size_t)b * MPTS + sidx[colx]) * CDIM + c0x;
        const _Float16* fnp = featH + ((size_t)b * MPTS + n0 + (colx >> 4)) * CDIM + c0x;
#pragma unroll
        for (int j = 0; j < 4; j++) {
            fmv[j] = *(const half8*)(fmp + j * 8);
            fnv[j] = *(const half8*)(fnp + j * 8);
        }
    }
    __syncthreads();

    // ---- phase 2: h = relu(bn(pw1 @ pos_rel)) -> hbuf [col][64]
    {
        int col = tid >> 3, o0 = (tid & 7) * 8;
        float x0 = pr[0][col], x1 = pr[1][col], x2 = pr[2][col];
        half8 hv;
#pragma unroll
        for (int i = 0; i < 8; i++) {
            int o = o0 + i;
            float v = pw1[o * 3] * x0 + pw1[o * 3 + 1] * x1 + pw1[o * 3 + 2] * x2 + pb1[o];
            v = fmaxf(v * pinv[o] + psh[o], 0.f);
            hv[i] = (_Float16)v;
        }
        *(half8*)((char*)hbuf + swz128(col, o0 * 2)) = hv;
    }
    __syncthreads();

    // ---- phase 3: pe GEMM + epilogue -> xbuf (as pe) AND registers pe4
    f32x4 acc[2][4];
#pragma unroll
    for (int rt = 0; rt < 2; rt++)
#pragma unroll
        for (int ct = 0; ct < 4; ct++) acc[rt][ct] = (f32x4){0.f, 0.f, 0.f, 0.f};
#pragma unroll
    for (int ks = 0; ks < 2; ks++) {
        int k0 = ks * 32 + l4 * 8;
#pragma unroll
        for (int ct = 0; ct < 4; ct++) {
            half8 bb = *(const half8*)((char*)hbuf + swz128(ct * 16 + l15, k0 * 2));
            acc[0][ct] = __builtin_amdgcn_mfma_f32_16x16x32_f16(wp[0][ks], bb, acc[0][ct], 0, 0, 0);
            acc[1][ct] = __builtin_amdgcn_mfma_f32_16x16x32_f16(wp[1][ks], bb, acc[1][ct], 0, 0, 0);
        }
    }
    half4 pe4[2][4];
#pragma unroll
    for (int rt = 0; rt < 2; rt++) {
        int cb = R0 + rt * 16 + 4 * l4;
        float4 pb = *(const float4*)(pb2 + cb);
        float pbv[4] = {pb.x, pb.y, pb.z, pb.w};
#pragma unroll
        for (int ct = 0; ct < 4; ct++) {
            int col = ct * 16 + l15;
            half4 p4;
#pragma unroll
            for (int r = 0; r < 4; r++) p4[r] = (_Float16)(acc[rt][ct][r] + pbv[r]);
            pe4[rt][ct] = p4;
            *(half4*)((char*)xbuf + swzS(col, cb * 2)) = p4;
        }
    }
    __syncthreads();

    // ---- phase 4: x = fn - fm + pe, in-place on xbuf; preload aw1 rt0 only
#pragma unroll
    for (int j = 0; j < 4; j++) {
        int c = c0x + j * 8;
        half8 vp = *(const half8*)((char*)xbuf + swzS(colx, c * 2));
        half8 xv = fnv[j] - fmv[j] + vp;
        *(half8*)((char*)xbuf + swzS(colx, c * 2)) = xv;
    }
    half8 wa[8];
#pragma unroll
    for (int ks = 0; ks < 8; ks++)
        wa[ks] = *(const half8*)(aw1h + (size_t)(R0 + l15) * 256 + ks * 32 + l4 * 8);
    __syncthreads();

    // ---- phase 5: GEMM1, one rt at a time (32 weight regs peak)
#pragma unroll
    for (int rt = 0; rt < 2; rt++)
#pragma unroll
        for (int ct = 0; ct < 4; ct++) acc[rt][ct] = (f32x4){0.f, 0.f, 0.f, 0.f};
#pragma unroll
    for (int ks = 0; ks < 8; ks++) {
        int k0 = ks * 32 + l4 * 8;
#pragma unroll
        for (int ct = 0; ct < 4; ct++) {
            half8 bb = *(const half8*)((char*)xbuf + swzS(ct * 16 + l15, k0 * 2));
            acc[0][ct] = __builtin_amdgcn_mfma_f32_16x16x32_f16(wa[ks], bb, acc[0][ct], 0, 0, 0);
        }
    }
#pragma unroll
    for (int ks = 0; ks < 8; ks++)
        wa[ks] = *(const half8*)(aw1h + (size_t)(R0 + 16 + l15) * 256 + ks * 32 + l4 * 8);
#pragma unroll
    for (int ks = 0; ks < 8; ks++) {
        int k0 = ks * 32 + l4 * 8;
#pragma unroll
        for (int ct = 0; ct < 4; ct++) {
            half8 bb = *(const half8*)((char*)xbuf + swzS(ct * 16 + l15, k0 * 2));
            acc[1][ct] = __builtin_amdgcn_mfma_f32_16x16x32_f16(wa[ks], bb, acc[1][ct], 0, 0, 0);
        }
    }
    __syncthreads();

    // ---- phase 6: a1 = relu(bn(.)) -> xbuf; preload aw2 rt0
#pragma unroll
    for (int rt = 0; rt < 2; rt++) {
        int cb = R0 + rt * 16 + 4 * l4;
        float4 iv = *(const float4*)(&ainv[cb]);
        float4 sh = *(const float4*)(&ash2[cb]);
        float ivv[4] = {iv.x, iv.y, iv.z, iv.w};
        float shv[4] = {sh.x, sh.y, sh.z, sh.w};
#pragma unroll
        for (int ct = 0; ct < 4; ct++) {
            int col = ct * 16 + l15;
            half4 h4;
#pragma unroll
            for (int r = 0; r < 4; r++)
                h4[r] = (_Float16)fmaxf(acc[rt][ct][r] * ivv[r] + shv[r], 0.f);
            *(half4*)((char*)xbuf + swzS(col, cb * 2)) = h4;
        }
    }
#pragma unroll
    for (int ks = 0; ks < 8; ks++)
        wa[ks] = *(const half8*)(aw2h + (size_t)(R0 + l15) * 256 + ks * 32 + l4 * 8);
    __syncthreads();

    // ---- phase 7: GEMM2, one rt at a time
#pragma unroll
    for (int rt = 0; rt < 2; rt++)
#pragma unroll
        for (int ct = 0; ct < 4; ct++) acc[rt][ct] = (f32x4){0.f, 0.f, 0.f, 0.f};
#pragma unroll
    for (int ks = 0; ks < 8; ks++) {
        int k0 = ks * 32 + l4 * 8;
#pragma unroll
        for (int ct = 0; ct < 4; ct++) {
            half8 bb = *(const half8*)((char*)xbuf + swzS(ct * 16 + l15, k0 * 2));
            acc[0][ct] = __builtin_amdgcn_mfma_f32_16x16x32_f16(wa[ks], bb, acc[0][ct], 0, 0, 0);
        }
    }
#pragma unroll
    for (int ks = 0; ks < 8; ks++)
        wa[ks] = *(const half8*)(aw2h + (size_t)(R0 + 16 + l15) * 256 + ks * 32 + l4 * 8);
#pragma unroll
    for (int ks = 0; ks < 8; ks++) {
        int k0 = ks * 32 + l4 * 8;
#pragma unroll
        for (int ct = 0; ct < 4; ct++) {
            half8 bb = *(const half8*)((char*)xbuf + swzS(ct * 16 + l15, k0 * 2));
            acc[1][ct] = __builtin_amdgcn_mfma_f32_16x16x32_f16(wa[ks], bb, acc[1][ct], 0, 0, 0);
        }
    }

    // ---- epilogue: gfa gather here (weights dead), DPP softmax, stores
#pragma unroll
    for (int rt = 0; rt < 2; rt++) {
        int cb = R0 + rt * 16 + 4 * l4;
        half4 gfa[4];
#pragma unroll
        for (int ct = 0; ct < 4; ct++)
            gfa[ct] = *(const half4*)(featH +
                ((size_t)b * MPTS + sidx[ct * 16 + l15]) * CDIM + cb);
#pragma unroll
        for (int ct = 0; ct < 4; ct++) {
            float oo[4], ss[4];
#pragma unroll
            for (int r = 0; r < 4; r++) {
                float v = acc[rt][ct][r];
                v = fminf(fmaxf(v, -60.f), 60.f);
                float e = __expf(v);
                float sv = (float)gfa[ct][r] + (float)pe4[rt][ct][r];
                ss[r] = sum16(e);
                oo[r] = sum16(e * sv);
            }
            if (l15 < 4) {
                float o = l15 == 0 ? oo[0] : l15 == 1 ? oo[1] : l15 == 2 ? oo[2] : oo[3];
                float s = l15 == 0 ? ss[0] : l15 == 1 ? ss[1] : l15 == 2 ? ss[2] : ss[3];
                out[((size_t)b * CDIM + cb + l15) * NPTS + n0 + ct] =
                    o * __builtin_amdgcn_rcpf(s);
            }
        }
    }
}

// ------------------------------------------------------------------- launch
extern "C" void kernel_launch(void* const* d_in, const int* in_sizes, int n_in,
                              void* d_out, int out_size, void* d_ws, size_t ws_size,
                              hipStream_t stream) {
    const float* pcd    = (const float*)d_in[0];
    const float* feat   = (const float*)d_in[1];
    const float* pcddb  = (const float*)d_in[2];
    const float* featdb = (const float*)d_in[3];
    const float* pw1 = (const float*)d_in[4];
    const float* pb1 = (const float*)d_in[5];
    const float* pg  = (const float*)d_in[6];
    const float* pbe = (const float*)d_in[7];
    const float* pm  = (const float*)d_in[8];
    const float* pv  = (const float*)d_in[9];
    const float* pw2 = (const float*)d_in[10];
    const float* pb2 = (const float*)d_in[11];
    const float* aw1 = (const float*)d_in[12];
    const float* ab1 = (const float*)d_in[13];
    const float* ag  = (const float*)d_in[14];
    const float* abe = (const float*)d_in[15];
    const float* am  = (const float*)d_in[16];
    const float* av  = (const float*)d_in[17];
    const float* aw2 = (const float*)d_in[18];
    // d_in[19] = ab2: constant over k -> cancels in softmax, unused
    float* out = (float*)d_out;

    char* ws = (char*)d_ws;
    _Float16* featH   = (_Float16*)(ws);               // 8 MB
    _Float16* featL   = (_Float16*)(ws + 8388608);     // 8 MB
    float*    ws_r2   = (float*)(ws + 16777216);       // 64 KB
    unsigned* partial = (unsigned*)(ws + 16842752);    // 4 MB
    int*      ws_idx  = (int*)(ws + 21037056);         // 512 KB
    _Float16* aw1h    = (_Float16*)(ws + 21561344);    // 128 KB
    _Float16* aw2h    = (_Float16*)(ws + 21692416);    // 128 KB
    _Float16* pw2h    = (_Float16*)(ws + 21823488);    // 32 KB

    wcvt<<<256, 256, 0, stream>>>(aw1, aw2, pw2, aw1h, aw2h, pw2h);
    tposeHL2<<<dim3(MPTS / 32, NB), 256, 0, stream>>>(feat, featdb, featH, featL, ws_r2);
    score_knn<<<dim3(NCHUNK, NPTS / QPB, NB), 1024, 0, stream>>>(featH, featL, ws_r2, partial);
    merge16<<<NB * NPTS / 256, 256, 0, stream>>>(partial, ws_idx);
    fused_mlp6<<<NB * (NPTS / 4), 512, 0, stream>>>(
        pcd, pcddb, featH, ws_idx,
        pw1, pb1, pg, pbe, pm, pv, pw2h, pb2,
        aw1h, ab1, ag, abe, am, av, aw2h, out);
}

// Round 16
// 254.367 us; speedup vs baseline: 1.1009x; 1.0494x over previous
//
#include <hip/hip_runtime.h>
#include <float.h>

#define CDIM 256
#define NPTS 2048
#define MPTS 4096
#define NB   4
#define KNN  16
#define COLS 128    // fused_mlp: NPB(8) * KNN
#define NPB  8
#define NCHUNK 8
#define CSIZE  512
#define NSTEPS 16
#define QPB   256   // score_knn queries per block (16 waves)

typedef _Float16 half8 __attribute__((ext_vector_type(8)));
typedef _Float16 half4 __attribute__((ext_vector_type(4)));
typedef float    f32x4 __attribute__((ext_vector_type(4)));

// swizzled byte offsets: row stride 512B / 128B
__device__ __forceinline__ int swzS(int row, int byte) {
    return row * 512 + (byte ^ ((row & 7) << 4));
}
__device__ __forceinline__ int swz128(int row, int byte) {
    return row * 128 + (byte ^ ((row & 7) << 4));
}

// 16-lane (DPP row) sum via rotations; every lane ends with the total.
__device__ __forceinline__ float sum16(float v) {
    v += __uint_as_float(__builtin_amdgcn_update_dpp(0, __float_as_uint(v), 0x128, 0xF, 0xF, true));
    v += __uint_as_float(__builtin_amdgcn_update_dpp(0, __float_as_uint(v), 0x124, 0xF, 0xF, true));
    v += __uint_as_float(__builtin_amdgcn_update_dpp(0, __float_as_uint(v), 0x122, 0xF, 0xF, true));
    v += __uint_as_float(__builtin_amdgcn_update_dpp(0, __float_as_uint(v), 0x121, 0xF, 0xF, true));
    return v;
}

// compare-exchange: kk ascending
#define CEA(x, y)                                                               \
    { unsigned lo_ = kk[x] < kk[y] ? kk[x] : kk[y];                             \
      unsigned hi_ = kk[x] < kk[y] ? kk[y] : kk[x];                             \
      kk[x] = lo_; kk[y] = hi_; }
// compare-exchange: td descending (max to lower index)
#define CED(x, y)                                                               \
    { unsigned hi_ = td[x] > td[y] ? td[x] : td[y];                             \
      unsigned lo_ = td[x] > td[y] ? td[y] : td[x];                             \
      td[x] = hi_; td[y] = lo_; }
// bitonic-16 -> sorted descending (spans 8,4,2,1)
#define RESORT16                                                                \
    CED(0,8) CED(1,9) CED(2,10) CED(3,11) CED(4,12) CED(5,13) CED(6,14) CED(7,15) \
    CED(0,4) CED(1,5) CED(2,6) CED(3,7) CED(8,12) CED(9,13) CED(10,14) CED(11,15) \
    CED(0,2) CED(1,3) CED(4,6) CED(5,7) CED(8,10) CED(9,11) CED(12,14) CED(13,15) \
    CED(0,1) CED(2,3) CED(4,5) CED(6,7) CED(8,9) CED(10,11) CED(12,13) CED(14,15)

// ------- (B,C,M) fp32 -> featH/featL (B,M,C) f16 hi/lo + r2, tiled & coalesced
__global__ __launch_bounds__(256) void tposeHL2(const float* __restrict__ feat,
                                                const float* __restrict__ featdb,
                                                _Float16* __restrict__ featH,
                                                _Float16* __restrict__ featL,
                                                float* __restrict__ r2) {
    __shared__ float red[8][33];
    const int b = blockIdx.y;
    const int mt = blockIdx.x;
    const int m = threadIdx.x & 31;
    const int cp = threadIdx.x >> 5;
    const int mg = mt * 32 + m;
    const float* src = (mg < NPTS) ? (feat + (size_t)b * CDIM * NPTS + mg)
                                   : (featdb + (size_t)b * CDIM * NPTS + (mg - NPTS));
    const int c0 = cp * 32;
    float acc = 0.f;
    half8 hh[4], ll[4];
#pragma unroll
    for (int i = 0; i < 32; i++) {
        float v = src[(size_t)(c0 + i) * NPTS];
        acc += v * v;
        _Float16 h = (_Float16)v;
        hh[i >> 3][i & 7] = h;
        ll[i >> 3][i & 7] = (_Float16)(v - (float)h);
    }
    _Float16* dh = featH + ((size_t)b * MPTS + mg) * CDIM + c0;
    _Float16* dl = featL + ((size_t)b * MPTS + mg) * CDIM + c0;
#pragma unroll
    for (int i = 0; i < 4; i++) {
        *(half8*)(dh + i * 8) = hh[i];
        *(half8*)(dl + i * 8) = ll[i];
    }
    red[cp][m] = acc;
    __syncthreads();
    if (threadIdx.x < 32) {
        float s = 0.f;
#pragma unroll
        for (int j = 0; j < 8; j++) s += red[j][threadIdx.x];
        r2[b * MPTS + mt * 32 + threadIdx.x] = s;
    }
}

// ------- weights fp32 -> f16
__global__ __launch_bounds__(256) void wcvt(const float* __restrict__ aw1,
                                            const float* __restrict__ aw2,
                                            const float* __restrict__ pw2,
                                            _Float16* __restrict__ aw1h,
                                            _Float16* __restrict__ aw2h,
                                            _Float16* __restrict__ pw2h) {
    int i = blockIdx.x * 256 + threadIdx.x;
    if (i < 65536) { aw1h[i] = (_Float16)aw1[i]; aw2h[i] = (_Float16)aw2[i]; }
    if (i < 16384) { pw2h[i] = (_Float16)pw2[i]; }
}

// ------- distance GEMM (f16 hi/lo refs) + bitonic top-16 (r15 verbatim)
__global__ __launch_bounds__(1024, 2) void score_knn(const _Float16* __restrict__ featH,
                                                     const _Float16* __restrict__ featL,
                                                     const float* __restrict__ r2g,
                                                     unsigned* __restrict__ partial) {
    __shared__ __align__(16) char sbuf[65536];   // 2 x (smH 16K | smL 16K)
    __shared__ float sr2[CSIZE];

    const int tid = threadIdx.x;
    const int lane = tid & 63, wave = tid >> 6;   // 16 waves
    const int l15 = lane & 15, l4 = lane >> 4;
    const int chunk = blockIdx.x, qt = blockIdx.y, b = blockIdx.z;
    const int nq = qt * QPB + wave * 16 + l15;
    const int m0 = chunk * CSIZE;

    if (tid < CSIZE) sr2[tid] = r2g[b * MPTS + m0 + tid];

    half8 qh[8], ql[8];
    {
        const _Float16* qb = featH + ((size_t)b * MPTS + nq) * CDIM + l4 * 8;
        const _Float16* qL = featL + ((size_t)b * MPTS + nq) * CDIM + l4 * 8;
#pragma unroll
        for (int ks = 0; ks < 8; ks++) {
            qh[ks] = *(const half8*)(qb + ks * 32);
            ql[ks] = *(const half8*)(qL + ks * 32);
        }
    }

    int adr[8];
#pragma unroll
    for (int ks = 0; ks < 8; ks++)
        adr[ks] = (ks * 4 + l4) * 512 + ((l15 * 16) ^ ((ks & 7) << 4));

    const int srow = tid >> 5;
    const int oo = tid & 31;
    const int wadr = oo * 512 + ((srow * 16) ^ (((oo >> 2) & 7) << 4));
    const char* gH = (const char*)(featH + ((size_t)b * MPTS + m0 + srow) * CDIM) + oo * 16;
    const char* gL = (const char*)(featL + ((size_t)b * MPTS + m0 + srow) * CDIM) + oo * 16;

    unsigned td[16];
#pragma unroll
    for (int i = 0; i < 16; i++) td[i] = 0xFFFFFFFFu;

    half8 pH = *(const half8*)gH;
    half8 pL = *(const half8*)gL;
    gH += 32 * CDIM * 2;
    gL += 32 * CDIM * 2;

    for (int s = 0; s < NSTEPS; ++s) {
        char* buf = sbuf + (s & 1) * 32768;
        *(half8*)(buf + wadr)         = pH;
        *(half8*)(buf + 16384 + wadr) = pL;
        __syncthreads();

        if (s < NSTEPS - 1) {
            pH = *(const half8*)gH;
            pL = *(const half8*)gL;
            gH += 32 * CDIM * 2;
            gL += 32 * CDIM * 2;
        }

        unsigned kk[8];
#pragma unroll
        for (int sub = 0; sub < 2; ++sub) {
            f32x4 a0 = {0.f, 0.f, 0.f, 0.f};
            f32x4 a1 = {0.f, 0.f, 0.f, 0.f};
            f32x4 a2 = {0.f, 0.f, 0.f, 0.f};
#pragma unroll
            for (int ks = 0; ks < 8; ks++) {
                half8 ah = *(const half8*)(buf + adr[ks] + sub * 256);
                half8 al = *(const half8*)(buf + 16384 + adr[ks] + sub * 256);
                a0 = __builtin_amdgcn_mfma_f32_16x16x32_f16(ah, qh[ks], a0, 0, 0, 0);
                a1 = __builtin_amdgcn_mfma_f32_16x16x32_f16(ah, ql[ks], a1, 0, 0, 0);
                a2 = __builtin_amdgcn_mfma_f32_16x16x32_f16(al, qh[ks], a2, 0, 0, 0);
            }
            float4 s4 = *(const float4*)(sr2 + s * 32 + sub * 16 + 4 * l4);
            const float sv[4] = {s4.x, s4.y, s4.z, s4.w};
            const int mloc0 = s * 32 + sub * 16 + 4 * l4;
#pragma unroll
            for (int r = 0; r < 4; r++) {
                float d = fmaxf(sv[r] - 2.f * (a0[r] + a1[r] + a2[r]), 0.f);
                unsigned dq = (unsigned)(d * 4096.f);
                dq = dq > 0x7FFFF0u ? 0x7FFFF0u : dq;
                kk[sub * 4 + r] = (dq << 9) | (unsigned)(mloc0 + r);
            }
        }
        CEA(0,1) CEA(2,3) CEA(4,5) CEA(6,7)
        CEA(0,2) CEA(1,3) CEA(4,6) CEA(5,7)
        CEA(1,2) CEA(5,6) CEA(0,4) CEA(3,7)
        CEA(1,5) CEA(2,6)
        CEA(1,4) CEA(3,6)
        CEA(2,4) CEA(3,5)
        CEA(3,4)
#pragma unroll
        for (int i = 0; i < 8; i++) td[i] = td[i] < kk[i] ? td[i] : kk[i];
        RESORT16
    }

#pragma unroll
    for (int rr = 0; rr < 2; rr++) {
        const int dx = 16 << rr;
        unsigned ot[16];
#pragma unroll
        for (int e = 0; e < 16; e++) ot[e] = __shfl_xor(td[e], dx);
#pragma unroll
        for (int e = 0; e < 16; e++) {
            unsigned o = ot[15 - e];
            td[e] = td[e] < o ? td[e] : o;
        }
        RESORT16
    }
    if (l4 == 0) {
        const size_t qrow = (size_t)b * NPTS + qt * QPB + wave * 16 + l15;
#pragma unroll
        for (int e = 0; e < 16; e++)
            partial[(size_t)(chunk * 16 + e) * (NB * NPTS) + qrow] = td[e];
    }
}

// ------- final merge: NCHUNK x 16 keys -> top-16 indices per row
__global__ __launch_bounds__(256) void merge16(const unsigned* __restrict__ partial,
                                               int* __restrict__ idxout) {
    const int row = blockIdx.x * 256 + threadIdx.x;
    unsigned long long td[16];
#pragma unroll
    for (int i = 0; i < 16; i++) td[i] = 0x8000000000ull + (unsigned long long)i;
    unsigned long long curmax = 0x800000000Full;
    for (int e = 0; e < NCHUNK * 16; e++) {
        unsigned k = partial[(size_t)e * (NB * NPTS) + row];
        unsigned long long k64 =
            (((unsigned long long)(k >> 9)) << 12) |
            (unsigned long long)((unsigned)((e >> 4) << 9) | (k & 0x1FFu));
        if (k64 < curmax) {
#pragma unroll
            for (int i_ = 0; i_ < 16; i_++) td[i_] = (td[i_] == curmax) ? k64 : td[i_];
            unsigned long long nm_ = td[0];
#pragma unroll
            for (int i_ = 1; i_ < 16; i_++) nm_ = td[i_] > nm_ ? td[i_] : nm_;
            curmax = nm_;
        }
    }
#pragma unroll
    for (int e = 0; e < 16; e++) idxout[row * 16 + e] = (int)(td[e] & 0xFFFull);
}

// ------- fused MLP chain, NPB=8: 1024 thr = 16 waves; each wave owns exactly
// 16 output channels (no rt loop). Weights amortized 2x per point; epilogue
// writes 32B/row-line (halved write amplification). LDS ~84 KB, 1 block/CU.
__global__ __launch_bounds__(1024, 4) void fused_mlp8(
    const float* __restrict__ pcd, const float* __restrict__ pcddb,
    const _Float16* __restrict__ featH, const int* __restrict__ knn,
    const float* __restrict__ pw1, const float* __restrict__ pb1,
    const float* __restrict__ pg, const float* __restrict__ pbe,
    const float* __restrict__ pm, const float* __restrict__ pv,
    const _Float16* __restrict__ pw2h, const float* __restrict__ pb2,
    const _Float16* __restrict__ aw1h, const float* __restrict__ ab1,
    const float* __restrict__ ag, const float* __restrict__ abe,
    const float* __restrict__ am, const float* __restrict__ av,
    const _Float16* __restrict__ aw2h,
    float* __restrict__ out) {
    __shared__ __align__(16) _Float16 xbuf[COLS * 256];   // 64 KB: pe -> x -> a1
    __shared__ __align__(16) _Float16 hbuf[COLS * 64];    // 16 KB
    __shared__ __align__(16) float pr[3][COLS];
    __shared__ int sidx[COLS];
    __shared__ __align__(16) float ainv[256], ash2[256], pinv[64], psh[64];

    const int tid = threadIdx.x;
    const int lane = tid & 63, wave = tid >> 6;   // 16 waves
    const int l15 = lane & 15, l4 = lane >> 4;
    const int blk = blockIdx.x;
    const int b = blk >> 8;
    const int n0 = (blk & 255) * NPB;
    const int R0 = wave * 16;                     // 16 channels per wave

    // ---- phase 0: consts + sidx; preload pw2 fragments (8 regs)
    if (tid < COLS) {
        sidx[tid] = knn[(size_t)(b * NPTS + n0 + (tid >> 4)) * KNN + (tid & 15)];
    } else if (tid < COLS + 256) {
        int c = tid - COLS;
        float inv = ag[c] / sqrtf(av[c] + 1e-5f);
        ainv[c] = inv;
        ash2[c] = abe[c] - am[c] * inv + ab1[c] * inv;
    } else if (tid < COLS + 256 + 64) {
        int o = tid - COLS - 256;
        float inv = pg[o] / sqrtf(pv[o] + 1e-5f);
        pinv[o] = inv;
        psh[o] = pbe[o] - pm[o] * inv;
    }
    half8 wp[2];
#pragma unroll
    for (int ks = 0; ks < 2; ks++)
        wp[ks] = *(const half8*)(pw2h + (size_t)(R0 + l15) * 64 + ks * 32 + l4 * 8);
    __syncthreads();

    // ---- phase 1: pr gather + fm/fn prefetch (T14)
    if (tid < 3 * COLS) {
        int c = tid >> 7, col = tid & (COLS - 1);
        int m = sidx[col];
        const float* pc = pcd + ((size_t)b * 3 + c) * NPTS;
        const float* px = pcddb + ((size_t)b * 3 + c) * NPTS;
        float gp = (m < NPTS) ? pc[m] : px[m - NPTS];
        pr[c][col] = pc[n0 + (col >> 4)] - gp;
    }
    const int colx = tid & (COLS - 1);
    const int c0x = (tid >> 7) * 32;              // 8 groups x 32 channels
    half8 fmv[4], fnv[4];
    {
        const _Float16* fmp = featH + ((size_t)b * MPTS + sidx[colx]) * CDIM + c0x;
        const _Float16* fnp = featH + ((size_t)b * MPTS + n0 + (colx >> 4)) * CDIM + c0x;
#pragma unroll
        for (int j = 0; j < 4; j++) {
            fmv[j] = *(const half8*)(fmp + j * 8);
            fnv[j] = *(const half8*)(fnp + j * 8);
        }
    }
    __syncthreads();

    // ---- phase 2: h = relu(bn(pw1 @ pos_rel)) -> hbuf [col][64]
    {
        int col = tid >> 3, o0 = (tid & 7) * 8;
        float x0 = pr[0][col], x1 = pr[1][col], x2 = pr[2][col];
        half8 hv;
#pragma unroll
        for (int i = 0; i < 8; i++) {
            int o = o0 + i;
            float v = pw1[o * 3] * x0 + pw1[o * 3 + 1] * x1 + pw1[o * 3 + 2] * x2 + pb1[o];
            v = fmaxf(v * pinv[o] + psh[o], 0.f);
            hv[i] = (_Float16)v;
        }
        *(half8*)((char*)hbuf + swz128(col, o0 * 2)) = hv;
    }
    __syncthreads();

    // ---- phase 3: pe GEMM (16 rows/wave) -> xbuf (as pe) AND registers pe4
    f32x4 acc[8];
#pragma unroll
    for (int ct = 0; ct < 8; ct++) acc[ct] = (f32x4){0.f, 0.f, 0.f, 0.f};
#pragma unroll
    for (int ks = 0; ks < 2; ks++) {
#pragma unroll
        for (int ct = 0; ct < 8; ct++) {
            half8 bb = *(const half8*)((char*)hbuf +
                                       swz128(ct * 16 + l15, (ks * 32 + l4 * 8) * 2));
            acc[ct] = __builtin_amdgcn_mfma_f32_16x16x32_f16(wp[ks], bb, acc[ct], 0, 0, 0);
        }
    }
    const int cb = R0 + 4 * l4;
    half4 pe4[8];
    {
        float4 pb = *(const float4*)(pb2 + cb);
        float pbv[4] = {pb.x, pb.y, pb.z, pb.w};
#pragma unroll
        for (int ct = 0; ct < 8; ct++) {
            int col = ct * 16 + l15;
            half4 p4;
#pragma unroll
            for (int r = 0; r < 4; r++) p4[r] = (_Float16)(acc[ct][r] + pbv[r]);
            pe4[ct] = p4;
            *(half4*)((char*)xbuf + swzS(col, cb * 2)) = p4;
        }
    }
    __syncthreads();

    // ---- phase 4: x = fn - fm + pe, in-place on xbuf; preload aw1
#pragma unroll
    for (int j = 0; j < 4; j++) {
        int c = c0x + j * 8;
        half8 vp = *(const half8*)((char*)xbuf + swzS(colx, c * 2));
        half8 xv = fnv[j] - fmv[j] + vp;
        *(half8*)((char*)xbuf + swzS(colx, c * 2)) = xv;
    }
    half8 wa[8];
#pragma unroll
    for (int ks = 0; ks < 8; ks++)
        wa[ks] = *(const half8*)(aw1h + (size_t)(R0 + l15) * 256 + ks * 32 + l4 * 8);
    __syncthreads();

    // ---- phase 5: GEMM1 (16 rows/wave, 8 col-tiles)
#pragma unroll
    for (int ct = 0; ct < 8; ct++) acc[ct] = (f32x4){0.f, 0.f, 0.f, 0.f};
#pragma unroll
    for (int ks = 0; ks < 8; ks++) {
        int k0 = ks * 32 + l4 * 8;
#pragma unroll
        for (int ct = 0; ct < 8; ct++) {
            half8 bb = *(const half8*)((char*)xbuf + swzS(ct * 16 + l15, k0 * 2));
            acc[ct] = __builtin_amdgcn_mfma_f32_16x16x32_f16(wa[ks], bb, acc[ct], 0, 0, 0);
        }
    }
    __syncthreads();

    // ---- phase 6: a1 = relu(bn(.)) -> xbuf; preload aw2
    {
        float4 iv = *(const float4*)(&ainv[cb]);
        float4 sh = *(const float4*)(&ash2[cb]);
        float ivv[4] = {iv.x, iv.y, iv.z, iv.w};
        float shv[4] = {sh.x, sh.y, sh.z, sh.w};
#pragma unroll
        for (int ct = 0; ct < 8; ct++) {
            int col = ct * 16 + l15;
            half4 h4;
#pragma unroll
            for (int r = 0; r < 4; r++)
                h4[r] = (_Float16)fmaxf(acc[ct][r] * ivv[r] + shv[r], 0.f);
            *(half4*)((char*)xbuf + swzS(col, cb * 2)) = h4;
        }
    }
#pragma unroll
    for (int ks = 0; ks < 8; ks++)
        wa[ks] = *(const half8*)(aw2h + (size_t)(R0 + l15) * 256 + ks * 32 + l4 * 8);
    __syncthreads();

    // ---- phase 7: GEMM2
#pragma unroll
    for (int ct = 0; ct < 8; ct++) acc[ct] = (f32x4){0.f, 0.f, 0.f, 0.f};
#pragma unroll
    for (int ks = 0; ks < 8; ks++) {
        int k0 = ks * 32 + l4 * 8;
#pragma unroll
        for (int ct = 0; ct < 8; ct++) {
            half8 bb = *(const half8*)((char*)xbuf + swzS(ct * 16 + l15, k0 * 2));
            acc[ct] = __builtin_amdgcn_mfma_f32_16x16x32_f16(wa[ks], bb, acc[ct], 0, 0, 0);
        }
    }

    // ---- epilogue: gfa gather (weights dead), DPP softmax, stores
#pragma unroll
    for (int ct = 0; ct < 8; ct++) {
        half4 gfa = *(const half4*)(featH +
            ((size_t)b * MPTS + sidx[ct * 16 + l15]) * CDIM + cb);
        float oo[4], ss[4];
#pragma unroll
        for (int r = 0; r < 4; r++) {
            float v = acc[ct][r];
            v = fminf(fmaxf(v, -60.f), 60.f);
            float e = __expf(v);
            float sv = (float)gfa[r] + (float)pe4[ct][r];
            ss[r] = sum16(e);
            oo[r] = sum16(e * sv);
        }
        if (l15 < 4) {
            float o = l15 == 0 ? oo[0] : l15 == 1 ? oo[1] : l15 == 2 ? oo[2] : oo[3];
            float s = l15 == 0 ? ss[0] : l15 == 1 ? ss[1] : l15 == 2 ? ss[2] : ss[3];
            out[((size_t)b * CDIM + cb + l15) * NPTS + n0 + ct] =
                o * __builtin_amdgcn_rcpf(s);
        }
    }
}

// ------------------------------------------------------------------- launch
extern "C" void kernel_launch(void* const* d_in, const int* in_sizes, int n_in,
                              void* d_out, int out_size, void* d_ws, size_t ws_size,
                              hipStream_t stream) {
    const float* pcd    = (const float*)d_in[0];
    const float* feat   = (const float*)d_in[1];
    const float* pcddb  = (const float*)d_in[2];
    const float* featdb = (const float*)d_in[3];
    const float* pw1 = (const float*)d_in[4];
    const float* pb1 = (const float*)d_in[5];
    const float* pg  = (const float*)d_in[6];
    const float* pbe = (const float*)d_in[7];
    const float* pm  = (const float*)d_in[8];
    const float* pv  = (const float*)d_in[9];
    const float* pw2 = (const float*)d_in[10];
    const float* pb2 = (const float*)d_in[11];
    const float* aw1 = (const float*)d_in[12];
    const float* ab1 = (const float*)d_in[13];
    const float* ag  = (const float*)d_in[14];
    const float* abe = (const float*)d_in[15];
    const float* am  = (const float*)d_in[16];
    const float* av  = (const float*)d_in[17];
    const float* aw2 = (const float*)d_in[18];
    // d_in[19] = ab2: constant over k -> cancels in softmax, unused
    float* out = (float*)d_out;

    char* ws = (char*)d_ws;
    _Float16* featH   = (_Float16*)(ws);               // 8 MB
    _Float16* featL   = (_Float16*)(ws + 8388608);     // 8 MB
    float*    ws_r2   = (float*)(ws + 16777216);       // 64 KB
    unsigned* partial = (unsigned*)(ws + 16842752);    // 4 MB
    int*      ws_idx  = (int*)(ws + 21037056);         // 512 KB
    _Float16* aw1h    = (_Float16*)(ws + 21561344);    // 128 KB
    _Float16* aw2h    = (_Float16*)(ws + 21692416);    // 128 KB
    _Float16* pw2h    = (_Float16*)(ws + 21823488);    // 32 KB

    wcvt<<<256, 256, 0, stream>>>(aw1, aw2, pw2, aw1h, aw2h, pw2h);
    tposeHL2<<<dim3(MPTS / 32, NB), 256, 0, stream>>>(feat, featdb, featH, featL, ws_r2);
    score_knn<<<dim3(NCHUNK, NPTS / QPB, NB), 1024, 0, stream>>>(featH, featL, ws_r2, partial);
    merge16<<<NB * NPTS / 256, 256, 0, stream>>>(partial, ws_idx);
    fused_mlp8<<<NB * (NPTS / NPB), 1024, 0, stream>>>(
        pcd, pcddb, featH, ws_idx,
        pw1, pb1, pg, pbe, pm, pv, pw2h, pb2,
        aw1h, ab1, ag, abe, am, av, aw2h, out);
}